// Round 12
// baseline (1633.895 us; speedup 1.0000x reference)
//
#include <hip/hip_runtime.h>
#include <math.h>

#define NN 50000
#define DD 128
#define HH 4
#define DHH 32
#define EE 600000
#define N2 (2*NN)
#define NBLK 256
#define NBUCK ((N2 + 511)/512)   // 196 buckets of 512 joint-nodes

typedef unsigned short u16;
typedef unsigned int   u32;
typedef unsigned char  u8;
using short8 = __attribute__((ext_vector_type(8))) short;   // 8 bf16 = 4 VGPRs (MFMA A/B frag)
using f32x4  = __attribute__((ext_vector_type(4))) float;   // MFMA C/D frag
using f32x2  = __attribute__((ext_vector_type(2))) float;

#define LOG2E 1.44269504f

__device__ __forceinline__ float lrelu(float v){ return v > 0.f ? v : 0.2f*v; }
__device__ __forceinline__ float gelu_exact(float x){ return 0.5f*x*(1.f+erff(x*0.70710678118654752f)); }
__device__ __forceinline__ u16 f2bf(float f){
  u32 u = __float_as_uint(f);
  u32 r = (u + 0x7fffu + ((u>>16)&1u)) >> 16;
  return (u16)r;
}
__device__ __forceinline__ u32 pack2bf(float a, float b){ return (u32)f2bf(a) | ((u32)f2bf(b)<<16); }
__device__ __forceinline__ float bflo(u32 u){ return __uint_as_float(u<<16); }
__device__ __forceinline__ float bfhi(u32 u){ return __uint_as_float(u & 0xffff0000u); }

// ---------------- fused prep: weights transpose+cast | fold_qA | film ----------------
__global__ __launch_bounds__(256) void prep_all(
    const float* __restrict__ gat_W, const float* __restrict__ Wk, const float* __restrict__ Wv,
    const float* __restrict__ Wo, const float* __restrict__ injW, u16* __restrict__ WT,
    const float* __restrict__ Wq, const float* __restrict__ bq, const float* __restrict__ a_rel,
    u16* __restrict__ wqtT, float* __restrict__ bqt,
    const float* __restrict__ z, const float* __restrict__ fW1, const float* __restrict__ fb1,
    const float* __restrict__ fW2, const float* __restrict__ fb2, float* __restrict__ gb){
  __shared__ float t[32][33];
  __shared__ float hsh[256];
  const int bid = blockIdx.x;
  if(bid < 128){
    const int m = bid >> 4, tile = bid & 15, tr = tile>>2, tc = tile&3;
    const float* src = (m<4) ? (gat_W + (size_t)m*16384) : (m==4? Wk : m==5? Wv : m==6? Wo : injW);
    const int lr = threadIdx.x>>5, lc = threadIdx.x&31;
    #pragma unroll
    for(int p=0;p<4;++p) t[lr+p*8][lc] = src[(size_t)(tr*32+lr+p*8)*128 + tc*32+lc];
    __syncthreads();
    #pragma unroll
    for(int p=0;p<4;++p)
      WT[(size_t)m*16384 + (size_t)(tc*32+lr+p*8)*128 + tr*32+lc] = f2bf(t[lc][lr+p*8]);
  } else if(bid < 257){
    int idx = (bid-128)*256 + threadIdx.x;
    if(idx < 2*128*129){
      int tt = idx / (128*129);
      int r = idx % (128*129);
      int f = r / 129, c = r % 129;
      int h = f>>5, m = f&31;
      const float* srcp = (c<128) ? (Wq + (size_t)c*128 + h*DHH) : (bq + h*DHH);
      const float* arow = a_rel + (((size_t)(tt*HH+h)*DHH)+m)*DHH;
      float s=0.f;
      #pragma unroll
      for(int e=0;e<DHH;++e) s = fmaf(srcp[e], arow[e], s);
      if(c<128) wqtT[(size_t)tt*16384 + (size_t)f*128 + c] = f2bf(s);
      else      bqt[tt*128 + f] = s;
    }
  } else {
    int j = threadIdx.x;
    float acc = fb1[j];
    for(int d=0; d<DD; ++d) acc = fmaf(z[d], fW1[d*256+j], acc);
    hsh[j] = gelu_exact(acc);
    __syncthreads();
    float acc2 = fb2[j];
    for(int k=0;k<256;++k) acc2 = fmaf(hsh[k], fW2[k*256+j], acc2);
    gb[j] = acc2;
  }
}

// ---------------- CSR build via bucket counting sort ----------------
// 1) bucket histogram (LDS-aggregated)
__global__ __launch_bounds__(256) void bucket_count(const int* __restrict__ d0, const int* __restrict__ d1,
                                                    int* __restrict__ bcnt){
  __shared__ int h[NBUCK];
  for(int i=threadIdx.x;i<NBUCK;i+=256) h[i]=0;
  __syncthreads();
  const int e0 = blockIdx.x*4096 + threadIdx.x;
  #pragma unroll
  for(int j=0;j<16;++j){
    int e = e0 + j*256;
    if(e < EE)           atomicAdd(&h[d0[e]>>9], 1);
    else if(e < 2*EE)    atomicAdd(&h[(NN + d1[e-EE])>>9], 1);
  }
  __syncthreads();
  for(int i=threadIdx.x;i<NBUCK;i+=256){ int v=h[i]; if(v) atomicAdd(&bcnt[i], v); }
}

// 2) scan bucket counts -> bbase/bcur
__global__ void bucket_scan(const int* __restrict__ bcnt, int* __restrict__ bbase, int* __restrict__ bcur){
  __shared__ int sh[256];
  int t=threadIdx.x;
  int v = (t<NBUCK)? bcnt[t] : 0;
  sh[t]=v; __syncthreads();
  for(int off=1;off<256;off<<=1){
    int u=(t>=off)?sh[t-off]:0; __syncthreads();
    sh[t]+=u; __syncthreads();
  }
  if(t<NBUCK){ bbase[t]=sh[t]-v; bcur[t]=sh[t]-v; }
  if(t==0) bbase[NBUCK] = 2*EE;
}

// 3) scatter packed (dloc|src) into contiguous bucket regions
__global__ void fill_bucket(const int* __restrict__ ei0, const int* __restrict__ ei1,
                            int* __restrict__ bcur, u32* __restrict__ eb){
  int e = blockIdx.x*blockDim.x+threadIdx.x;
  int d, src;
  if(e < EE){ d = ei0[EE+e]; src = ei0[e]; }
  else if(e < 2*EE){ int i=e-EE; d = NN + ei1[EE+i]; src = ei1[i]; }
  else return;
  int b = d>>9, dloc = d & 511;
  int pos = atomicAdd(&bcur[b], 1);
  eb[pos] = ((u32)dloc<<16) | (u32)src;
}

// 4) per-bucket: node histogram + scan -> jrs, then place edges into es
__global__ __launch_bounds__(256) void fill_place(const u32* __restrict__ eb, const int* __restrict__ bbase,
                                                  int* __restrict__ jrs, u16* __restrict__ es){
  const int b = blockIdx.x;
  const int nb0 = b*512;
  const int nloc = min(512, N2-nb0);
  const int base = bbase[b], end = bbase[b+1];
  __shared__ int hist[512];
  __shared__ int psum[256];
  const int t = threadIdx.x;
  hist[t]=0; hist[t+256]=0;
  __syncthreads();
  for(int p=base+t; p<end; p+=256) atomicAdd(&hist[eb[p]>>16], 1);
  __syncthreads();
  const int c0 = hist[2*t], c1 = hist[2*t+1];
  const int pair = c0+c1;
  psum[t]=pair; __syncthreads();
  for(int off=1;off<256;off<<=1){
    int u=(t>=off)?psum[t-off]:0; __syncthreads();
    psum[t]+=u; __syncthreads();
  }
  const int ex = base + psum[t]-pair;   // global start of node 2t
  if(2*t   < nloc) jrs[nb0+2*t]   = ex;
  if(2*t+1 < nloc) jrs[nb0+2*t+1] = ex+c0;
  __syncthreads();
  hist[2*t]=ex; hist[2*t+1]=ex+c0;      // reuse as cursors
  __syncthreads();
  for(int p=base+t; p<end; p+=256){
    u32 w = eb[p];
    int pos = atomicAdd(&hist[w>>16], 1);
    es[pos] = (u16)(w & 0xffffu);
  }
  if(b==0 && t==0) jrs[N2] = 2*EE;
}

// ---------------- MFMA GEMM ----------------
constexpr int MM_BIAS  = 1;
constexpr int MM_FILM  = 2;   // o += base[row,c]; o = fgb[c]*o + fgb[128+c]
constexpr int MM_SKIP  = 4;   // o = sk*o + (1-sk)*base[row,c]
constexpr int MM_ABF16 = 64;  // A input is bf16

#define SWZ(row, byte) ((byte) ^ (((row)&7)<<4))

template<int MODE>
__device__ __forceinline__ void mgemm_core(const void* Av, const u16* WT, int row0, int n,
                                           u16* Al, u16* Wl, f32x4 (&acc)[8]){
  const int tid = threadIdx.x;
  if(MODE & MM_ABF16){
    const uint2* Ag = (const uint2*)((const u16*)Av + (size_t)row0*128);
    const int maxv = (min(64, n-row0))*32;
    #pragma unroll
    for(int j=0;j<8;++j){
      int v = tid + j*256;
      uint2 st = make_uint2(0u,0u);
      if(v < maxv) st = Ag[v];
      int row = v>>5, cb = (v&31)*8;
      *(uint2*)((char*)Al + row*256 + SWZ(row, cb)) = st;
    }
  } else {
    const float4* Ag = (const float4*)((const float*)Av + (size_t)row0*128);
    const int maxv = (min(64, n-row0))*32;
    #pragma unroll
    for(int j=0;j<8;++j){
      int v = tid + j*256;
      float4 val = make_float4(0.f,0.f,0.f,0.f);
      if(v < maxv) val = Ag[v];
      int row = v>>5, cb = (v&31)*8;
      uint2 st; st.x = pack2bf(val.x, val.y); st.y = pack2bf(val.z, val.w);
      *(uint2*)((char*)Al + row*256 + SWZ(row, cb)) = st;
    }
  }
  {
    const u32* Wg = (const u32*)WT;
    #pragma unroll
    for(int j=0;j<32;++j){
      int v = tid + j*256;
      u32 w = Wg[v];
      int row = v>>6, cb = (v&63)*4;
      *(u32*)((char*)Wl + row*256 + SWZ(row, cb)) = w;
    }
  }
  __syncthreads();
  const int lane = tid & 63;
  const int wv   = tid >> 6;
  const int r16  = lane & 15;
  const int kg   = lane >> 4;
  #pragma unroll
  for(int nn=0;nn<8;++nn) acc[nn] = (f32x4){0.f,0.f,0.f,0.f};
  #pragma unroll
  for(int s=0;s<4;++s){
    const int arow = wv*16 + r16;
    const int kb = s*64 + kg*16;
    short8 af = *(const short8*)((const char*)Al + arow*256 + SWZ(arow, kb));
    #pragma unroll
    for(int nn=0;nn<8;++nn){
      const int brow = nn*16 + r16;
      short8 bf = *(const short8*)((const char*)Wl + brow*256 + SWZ(brow, kb));
      acc[nn] = __builtin_amdgcn_mfma_f32_16x16x32_bf16(af, bf, acc[nn], 0, 0, 0);
    }
  }
}

// single-job mgemm (f32 out) for Wo / inj epilogues
template<int MODE>
__global__ __launch_bounds__(256) void mgemm(const void* __restrict__ Av, const u16* __restrict__ WT,
    const float* __restrict__ bias, const float* __restrict__ base, const float* __restrict__ fgb,
    const float* __restrict__ skipv, float* __restrict__ C, int n){
  __shared__ u16 Al[64*128];
  __shared__ u16 Wl[128*128];
  const int row0 = blockIdx.x*64;
  f32x4 acc[8];
  mgemm_core<MODE>(Av, WT, row0, n, Al, Wl, acc);
  const int lane = threadIdx.x & 63;
  const int wv   = threadIdx.x >> 6;
  const int r16  = lane & 15;
  const int kg   = lane >> 4;
  float bvals[8];
  if(MODE & MM_BIAS){
    #pragma unroll
    for(int nn=0;nn<8;++nn) bvals[nn] = bias[nn*16+r16];
  }
  float sk = 0.f;
  if(MODE & MM_SKIP) sk = 1.f/(1.f+__expf(-skipv[0]));
  #pragma unroll
  for(int i=0;i<4;++i){
    const int row = row0 + wv*16 + kg*4 + i;
    if(row >= n) continue;
    #pragma unroll
    for(int nn=0;nn<8;++nn){
      const int col = nn*16 + r16;
      float o = acc[nn][i];
      if(MODE & MM_BIAS) o += bvals[nn];
      if(MODE & MM_SKIP)
        o = sk*o + (1.f-sk)*base[(size_t)row*128 + col];
      if(MODE & MM_FILM){
        o += base[(size_t)row*128 + col];
        o = fgb[col]*o + fgb[128+col];
      }
      C[(size_t)row*128 + col] = o;
    }
  }
}

// multi-job mgemm: stages A ONCE, loops jobs. sel: 1 = bf16 out, 2 = KV k fp8, 3 = KV v fp8
struct MJob {
  const u16* WT;
  const float* bias;   // nullptr = none
  const float* as_;    // nullptr = no ATT epilogue
  const float* ad_;
  void* Cv;
  int att_t;
  int sel;
};
struct MJobs { MJob j[4]; };

__global__ __launch_bounds__(256) void mgemmM(const float* __restrict__ Av, MJobs jobs, int njobs,
    float* __restrict__ als8, float* __restrict__ ald8, int n){
  __shared__ u16 Al[64*128];
  __shared__ u16 Wl[128*128];
  const int tid = threadIdx.x;
  const int row0 = blockIdx.x*64;
  { // stage A once (f32 -> bf16)
    const float4* Ag = (const float4*)(Av + (size_t)row0*128);
    const int maxv = (min(64, n-row0))*32;
    #pragma unroll
    for(int j=0;j<8;++j){
      int v = tid + j*256;
      float4 val = make_float4(0.f,0.f,0.f,0.f);
      if(v < maxv) val = Ag[v];
      int row = v>>5, cb = (v&31)*8;
      uint2 st; st.x = pack2bf(val.x, val.y); st.y = pack2bf(val.z, val.w);
      *(uint2*)((char*)Al + row*256 + SWZ(row, cb)) = st;
    }
  }
  const int lane = tid & 63;
  const int wv   = tid >> 6;
  const int r16  = lane & 15;
  const int kg   = lane >> 4;
  for(int jj=0; jj<njobs; ++jj){
    const MJob job = jobs.j[jj];
    {
      const u32* Wg = (const u32*)job.WT;
      #pragma unroll
      for(int j=0;j<32;++j){
        int v = tid + j*256;
        u32 w = Wg[v];
        int row = v>>6, cb = (v&63)*4;
        *(u32*)((char*)Wl + row*256 + SWZ(row, cb)) = w;
      }
    }
    __syncthreads();
    f32x4 acc[8];
    #pragma unroll
    for(int nn=0;nn<8;++nn) acc[nn] = (f32x4){0.f,0.f,0.f,0.f};
    #pragma unroll
    for(int s=0;s<4;++s){
      const int arow = wv*16 + r16;
      const int kb = s*64 + kg*16;
      short8 af = *(const short8*)((const char*)Al + arow*256 + SWZ(arow, kb));
      #pragma unroll
      for(int nn=0;nn<8;++nn){
        const int brow = nn*16 + r16;
        short8 bf = *(const short8*)((const char*)Wl + brow*256 + SWZ(brow, kb));
        acc[nn] = __builtin_amdgcn_mfma_f32_16x16x32_bf16(af, bf, acc[nn], 0, 0, 0);
      }
    }
    if(job.as_){
      float asv[8], adv[8];
      #pragma unroll
      for(int nn=0;nn<8;++nn){ asv[nn]=job.as_[nn*16+r16]; adv[nn]=job.ad_[nn*16+r16]; }
      #pragma unroll
      for(int i=0;i<4;++i){
        const int row = row0 + wv*16 + kg*4 + i;
        #pragma unroll
        for(int h=0;h<4;++h){
          float ps = asv[2*h]*acc[2*h][i] + asv[2*h+1]*acc[2*h+1][i];
          float pd = adv[2*h]*acc[2*h][i] + adv[2*h+1]*acc[2*h+1][i];
          ps += __shfl_xor(ps,1); ps += __shfl_xor(ps,2); ps += __shfl_xor(ps,4); ps += __shfl_xor(ps,8);
          pd += __shfl_xor(pd,1); pd += __shfl_xor(pd,2); pd += __shfl_xor(pd,4); pd += __shfl_xor(pd,8);
          if(row < n && r16 == 0){
            als8[(size_t)row*8 + 2*h + job.att_t] = ps;
            ald8[(size_t)row*8 + 2*h + job.att_t] = pd;
          }
        }
      }
    }
    float bvals[8];
    #pragma unroll
    for(int nn=0;nn<8;++nn) bvals[nn] = job.bias ? job.bias[nn*16+r16] : 0.f;
    #pragma unroll
    for(int i=0;i<4;++i){
      const int row = row0 + wv*16 + kg*4 + i;
      if(row >= n) continue;
      #pragma unroll
      for(int nn=0;nn<8;++nn){
        const int col = nn*16 + r16;
        float o = acc[nn][i] + bvals[nn];
        if(job.sel == 1){
          ((u16*)job.Cv)[(size_t)row*128 + col] = f2bf(o);
        } else {
          u32 enc = __builtin_amdgcn_cvt_pk_fp8_f32(o, 0.f, 0u, false);
          ((u8*)job.Cv)[(size_t)row*256 + (col>>1)*4 + (col&1) + (job.sel-2)*2] = (u8)(enc & 0xffu);
        }
      }
    }
    __syncthreads();
  }
}

// ---------------- GAT merged gather: both types, per-type xp tables (bf16) ----------------
__global__ __launch_bounds__(256) void gat_gather3(const u16* __restrict__ xp0, const u16* __restrict__ xp1,
    const float* __restrict__ als8, const float* __restrict__ ald8,
    const int* __restrict__ jrs, const u16* __restrict__ es,
    const float* __restrict__ gb0, const float* __restrict__ gb1, float* __restrict__ out){
  const int gid = blockIdx.x*blockDim.x + threadIdx.x;
  const int node = gid >> 6;
  const int lane = threadIdx.x & 63;
  if(node >= NN) return;
  const int h = lane >> 4;
  const int cc = 2*lane;
  float o0 = gb0[cc] + gb1[cc], o1 = gb0[cc+1] + gb1[cc+1];
  #pragma unroll
  for(int t=0;t<2;++t){
    const u16* __restrict__ xp = t ? xp1 : xp0;
    const float aldv = ald8[(size_t)node*8 + 2*h + t];
    const int s0 = jrs[t*NN+node], s1 = jrs[t*NN+node+1];
    float ssum=0.f, a0=0.f, a1=0.f;
    int p = s0;
    for(; p+3<s1; p+=4){
      const int sA = es[p], sB = es[p+1], sC = es[p+2], sD = es[p+3];
      const u32 xA = *(const u32*)&xp[(size_t)sA*DD + cc];
      const u32 xB = *(const u32*)&xp[(size_t)sB*DD + cc];
      const u32 xC = *(const u32*)&xp[(size_t)sC*DD + cc];
      const u32 xD = *(const u32*)&xp[(size_t)sD*DD + cc];
      float lA = als8[(size_t)sA*8 + 2*h + t] + aldv;
      float lB = als8[(size_t)sB*8 + 2*h + t] + aldv;
      float lC = als8[(size_t)sC*8 + 2*h + t] + aldv;
      float lD = als8[(size_t)sD*8 + 2*h + t] + aldv;
      const float eA = exp2f(lA>0.f ? lA*LOG2E : lA*(0.2f*LOG2E));
      const float eB = exp2f(lB>0.f ? lB*LOG2E : lB*(0.2f*LOG2E));
      const float eC = exp2f(lC>0.f ? lC*LOG2E : lC*(0.2f*LOG2E));
      const float eD = exp2f(lD>0.f ? lD*LOG2E : lD*(0.2f*LOG2E));
      ssum += (eA+eB)+(eC+eD);
      a0 = fmaf(eA, bflo(xA), a0); a1 = fmaf(eA, bfhi(xA), a1);
      a0 = fmaf(eB, bflo(xB), a0); a1 = fmaf(eB, bfhi(xB), a1);
      a0 = fmaf(eC, bflo(xC), a0); a1 = fmaf(eC, bfhi(xC), a1);
      a0 = fmaf(eD, bflo(xD), a0); a1 = fmaf(eD, bfhi(xD), a1);
    }
    for(; p<s1; ++p){
      const int sA = es[p];
      const u32 xA = *(const u32*)&xp[(size_t)sA*DD + cc];
      float lA = als8[(size_t)sA*8 + 2*h + t] + aldv;
      const float eA = exp2f(lA>0.f ? lA*LOG2E : lA*(0.2f*LOG2E));
      ssum += eA;
      a0 = fmaf(eA, bflo(xA), a0); a1 = fmaf(eA, bfhi(xA), a1);
    }
    { // self loop (appended in reference)
      float lg = als8[(size_t)node*8 + 2*h + t] + aldv;
      const float ev = exp2f(lg>0.f ? lg*LOG2E : lg*(0.2f*LOG2E));
      ssum += ev;
      const u32 xr = *(const u32*)&xp[(size_t)node*DD + cc];
      a0 = fmaf(ev, bflo(xr), a0); a1 = fmaf(ev, bfhi(xr), a1);
    }
    const float inv = 1.f/ssum;
    o0 = fmaf(a0, inv, o0); o1 = fmaf(a1, inv, o1);
  }
  *(float2*)&out[(size_t)node*DD + cc] = make_float2(o0, o1);
}

// ---------------- BN: stats + fenced last-block finalize (deterministic, parallel tail) ----------------
__global__ __launch_bounds__(256) void bn_stats_fused(const float* __restrict__ X, float* __restrict__ part,
                               const float* __restrict__ gamma, const float* __restrict__ beta,
                               float* __restrict__ stat, int* __restrict__ counter){
  const int f = threadIdx.x & 127, rg = threadIdx.x>>7;
  float s=0.f, s2=0.f;
  for(int r = blockIdx.x*2+rg; r<NN; r += NBLK*2){
    float v = X[(size_t)r*DD+f]; s+=v; s2 = fmaf(v,v,s2);
  }
  __shared__ float ls[256], ls2[256];
  __shared__ int lastsh;
  ls[threadIdx.x]=s; ls2[threadIdx.x]=s2; __syncthreads();
  if(rg==0){
    part[blockIdx.x*256 + f]       = ls[f]+ls[128+f];
    part[blockIdx.x*256 + 128 + f] = ls2[f]+ls2[128+f];
  }
  __threadfence();
  if(threadIdx.x==0) lastsh = (atomicAdd(counter,1) == NBLK-1);
  __syncthreads();
  if(lastsh){
    __threadfence();
    float ss=0.f, ss2=0.f;
    #pragma unroll 8
    for(int bk=rg; bk<NBLK; bk+=2){
      ss  += part[bk*256 + f];
      ss2 += part[bk*256 + 128 + f];
    }
    __syncthreads();
    ls[threadIdx.x]=ss; ls2[threadIdx.x]=ss2;
    __syncthreads();
    if(rg==0){
      float S1 = ls[f]+ls[128+f], S2 = ls2[f]+ls2[128+f];
      float mu = S1/(float)NN;
      float var = S2/(float)NN - mu*mu;
      float rs = rsqrtf(var+1e-5f);
      stat[f]     = gamma[f]*rs;
      stat[128+f] = beta[f] - gamma[f]*rs*mu;
    }
    if(threadIdx.x==0) *counter = 0;
  }
}

// out = lrelu(xprev + A*acc + B)
__global__ void bn_apply_lrelu(const float* __restrict__ xprev, const float* __restrict__ acc,
                               const float* __restrict__ stat, float* __restrict__ out){
  int idx = blockIdx.x*blockDim.x+threadIdx.x;
  if(idx >= NN*64) return;
  int c = (2*idx) & 127;
  float2 x = ((const float2*)xprev)[idx];
  float2 a = ((const float2*)acc)[idx];
  float o0 = lrelu(x.x + fmaf(stat[c],   a.x, stat[128+c]));
  float o1 = lrelu(x.y + fmaf(stat[c+1], a.y, stat[128+c+1]));
  ((float2*)out)[idx] = make_float2(o0,o1);
}

// ---------------- HGT merged edge kernel: qt tables + fp8 interleaved KV ----------------
__global__ __launch_bounds__(256) void hgt_merged2(const u16* __restrict__ qt,
    const u32* __restrict__ kv, const int* __restrict__ jrs, const u16* __restrict__ es,
    const float* __restrict__ p_rel, u16* __restrict__ Sv){
  const int gid = blockIdx.x*blockDim.x + threadIdx.x;
  const int node = gid >> 6;
  const int lane = threadIdx.x & 63;
  if(node >= NN) return;
  const int h = lane >> 4;
  float acc[2][2] = {{0.f,0.f},{0.f,0.f}};
  float ssum = 0.f;
  #pragma unroll
  for(int t=0;t<2;++t){
    const u32 qw = *(const u32*)&qt[(size_t)t*NN*DD + (size_t)node*DD + 2*lane];
    const float q0 = bflo(qw), q1 = bfhi(qw);
    const float scale2 = p_rel[t*HH+h]*(0.17677669529663687f*LOG2E);
    const int s0 = jrs[t*NN+node], s1 = jrs[t*NN+node+1];
    int p = s0;
    for(; p+3<s1; p+=4){
      const int sA = es[p], sB = es[p+1], sC = es[p+2], sD = es[p+3];
      const u32 wA = kv[(size_t)sA*64 + lane];
      const u32 wB = kv[(size_t)sB*64 + lane];
      const u32 wC = kv[(size_t)sC*64 + lane];
      const u32 wD = kv[(size_t)sD*64 + lane];
      f32x2 kA = __builtin_amdgcn_cvt_pk_f32_fp8(wA, false);
      f32x2 kB = __builtin_amdgcn_cvt_pk_f32_fp8(wB, false);
      f32x2 kC = __builtin_amdgcn_cvt_pk_f32_fp8(wC, false);
      f32x2 kD = __builtin_amdgcn_cvt_pk_f32_fp8(wD, false);
      f32x2 vA = __builtin_amdgcn_cvt_pk_f32_fp8(wA, true);
      f32x2 vB = __builtin_amdgcn_cvt_pk_f32_fp8(wB, true);
      f32x2 vC = __builtin_amdgcn_cvt_pk_f32_fp8(wC, true);
      f32x2 vD = __builtin_amdgcn_cvt_pk_f32_fp8(wD, true);
      float pA = q0*kA.x + q1*kA.y;
      float pB = q0*kB.x + q1*kB.y;
      float pC = q0*kC.x + q1*kC.y;
      float pD = q0*kD.x + q1*kD.y;
      pA += __shfl_xor(pA,1); pB += __shfl_xor(pB,1); pC += __shfl_xor(pC,1); pD += __shfl_xor(pD,1);
      pA += __shfl_xor(pA,2); pB += __shfl_xor(pB,2); pC += __shfl_xor(pC,2); pD += __shfl_xor(pD,2);
      pA += __shfl_xor(pA,4); pB += __shfl_xor(pB,4); pC += __shfl_xor(pC,4); pD += __shfl_xor(pD,4);
      pA += __shfl_xor(pA,8); pB += __shfl_xor(pB,8); pC += __shfl_xor(pC,8); pD += __shfl_xor(pD,8);
      const float eA=exp2f(pA*scale2), eB=exp2f(pB*scale2);
      const float eC=exp2f(pC*scale2), eD=exp2f(pD*scale2);
      ssum += (eA+eB)+(eC+eD);
      acc[t][0] = fmaf(eA, vA.x, acc[t][0]); acc[t][1] = fmaf(eA, vA.y, acc[t][1]);
      acc[t][0] = fmaf(eB, vB.x, acc[t][0]); acc[t][1] = fmaf(eB, vB.y, acc[t][1]);
      acc[t][0] = fmaf(eC, vC.x, acc[t][0]); acc[t][1] = fmaf(eC, vC.y, acc[t][1]);
      acc[t][0] = fmaf(eD, vD.x, acc[t][0]); acc[t][1] = fmaf(eD, vD.y, acc[t][1]);
    }
    for(; p<s1; ++p){
      const int sA = es[p];
      const u32 wA = kv[(size_t)sA*64 + lane];
      f32x2 kA = __builtin_amdgcn_cvt_pk_f32_fp8(wA, false);
      f32x2 vA = __builtin_amdgcn_cvt_pk_f32_fp8(wA, true);
      float pA = q0*kA.x + q1*kA.y;
      pA += __shfl_xor(pA,1); pA += __shfl_xor(pA,2); pA += __shfl_xor(pA,4); pA += __shfl_xor(pA,8);
      const float eA = exp2f(pA*scale2);
      ssum += eA;
      acc[t][0] = fmaf(eA, vA.x, acc[t][0]); acc[t][1] = fmaf(eA, vA.y, acc[t][1]);
    }
  }
  const float inv = ssum>0.f ? 1.f/ssum : 0.f;
  ((u32*)&Sv[(size_t)node*256 +       2*lane])[0] = pack2bf(acc[0][0]*inv, acc[0][1]*inv);
  ((u32*)&Sv[(size_t)node*256 + 128 + 2*lane])[0] = pack2bf(acc[1][0]*inv, acc[1][1]*inv);
}

// ---------------- post-aggregation m_rel transform + gelu (bf16 out) ----------------
__global__ __launch_bounds__(256) void mtransform_kernel(const u16* __restrict__ Sv, const float* __restrict__ m_rel,
                                                         u16* __restrict__ out){
  __shared__ float Msh[2*HH*DHH*DHH];   // 32 KB
  for(int i=threadIdx.x;i<2*HH*DHH*DHH;i+=256) Msh[i]=m_rel[i];
  __syncthreads();
  int idx = blockIdx.x*blockDim.x + threadIdx.x;
  if(idx >= NN*DD) return;
  int node = idx>>7, f = idx&127, h = f>>5, e = f&31;
  const u16* s0p = &Sv[(size_t)node*256 + h*DHH];
  const u16* s1p = &Sv[(size_t)node*256 + 128 + h*DHH];
  const float* M0 = &Msh[(0*HH+h)*DHH*DHH + e];
  const float* M1 = &Msh[(1*HH+h)*DHH*DHH + e];
  float s = 0.f;
  #pragma unroll
  for(int d=0; d<DHH; d+=2){
    u32 w0 = *(const u32*)&s0p[d];
    u32 w1 = *(const u32*)&s1p[d];
    s = fmaf(bflo(w0), M0[d*DHH],     s);
    s = fmaf(bfhi(w0), M0[(d+1)*DHH], s);
    s = fmaf(bflo(w1), M1[d*DHH],     s);
    s = fmaf(bfhi(w1), M1[(d+1)*DHH], s);
  }
  out[idx] = f2bf(gelu_exact(s));
}

// ---------------- host ----------------
extern "C" void kernel_launch(void* const* d_in, const int* in_sizes, int n_in,
                              void* d_out, int out_size, void* d_ws, size_t ws_size,
                              hipStream_t stream){
  const float* x_cell = (const float*)d_in[0];
  const float* z_h    = (const float*)d_in[1];
  const float* x_emb  = (const float*)d_in[2];
  const int*   ei0    = (const int*)d_in[3];
  const int*   ei1    = (const int*)d_in[4];
  const float* gat_W  = (const float*)d_in[5];
  const float* gat_as = (const float*)d_in[6];
  const float* gat_ad = (const float*)d_in[7];
  const float* gat_b  = (const float*)d_in[8];
  const float* bn_g   = (const float*)d_in[9];
  const float* bn_b   = (const float*)d_in[10];
  const float* Wk = (const float*)d_in[11];
  const float* bk = (const float*)d_in[12];
  const float* Wq = (const float*)d_in[13];
  const float* bq = (const float*)d_in[14];
  const float* Wv = (const float*)d_in[15];
  const float* bv = (const float*)d_in[16];
  const float* a_rel = (const float*)d_in[17];
  const float* m_rel = (const float*)d_in[18];
  const float* p_rel = (const float*)d_in[19];
  const float* Wo = (const float*)d_in[20];
  const float* bo = (const float*)d_in[21];
  const float* skip = (const float*)d_in[22];
  const float* injW = (const float*)d_in[23];
  const float* injb = (const float*)d_in[24];
  const float* fW1 = (const float*)d_in[25];
  const float* fb1 = (const float*)d_in[26];
  const float* fW2 = (const float*)d_in[27];
  const float* fb2 = (const float*)d_in[28];

  constexpr size_t SLOT = (size_t)NN*DD;   // 6.4M elements
  float* ws = (float*)d_ws;
  float* A    = ws;                       // pre-BN acc / QT tables (bf16 x2) / mtransform bf16 out
  float* X2   = A + SLOT;                 // x1 then x2 (f32)
  float* als8 = X2 + SLOT;                // NN*8  [node][2*h+t]
  float* ald8 = als8 + (size_t)NN*8;      // NN*8
  float* bnpart = ald8 + (size_t)NN*8;    // 256*256
  float* bnstat = bnpart + 256*256;       // 256
  float* fgb    = bnstat + 256;           // 256
  float* bqt    = fgb + 256;              // 2*128
  u16* WT8  = (u16*)(bqt + 2*128);        // 8 * 128*128 bf16 (transposed weights)
  u16* WQT  = WT8 + (size_t)8*16384;      // 2 * 128*128 bf16 (folded q weights, transposed)
  u16* S    = WQT + (size_t)2*16384;      // NN*256 bf16 (HGT Sv) ; eb (u32*2EE) aliases S
  u16* XP0  = S + (size_t)NN*256;         // NN*128 bf16 (xp type0) ; fp8 KV aliases XP0
  u16* XP1  = XP0 + SLOT;                 // NN*128 bf16 (xp type1)
  u16* es   = XP1 + SLOT;                 // 2*EE u16
  int* bcnt = (int*)(es + (size_t)2*EE + 2);  // NBUCK (memset with bnctr)
  int* bnctr= bcnt + NBUCK;               // 4 ints
  int* jrs  = bnctr + 4;                  // N2+1
  int* bbase= jrs + N2 + 2;               // NBUCK+1
  int* bcur = bbase + NBUCK + 2;          // NBUCK
  size_t needed = (size_t)((char*)(bcur + NBUCK + 2) - (char*)d_ws);
  if(ws_size < needed) return;  // insufficient scratch: fail loud (poisoned d_out)

  u16* QT = (u16*)A;            // 2 bf16 qt tables alias the A slot during HGT edge phase
  u16* MT = (u16*)A;            // mtransform bf16 out (QT dead by then)
  u32* KV = (u32*)XP0;          // fp8 interleaved k/v table: NN rows x 64 u32 (12.8 MB)
  u32* EB = (u32*)S;            // bucket-sorted packed edges (4.8 MB, aliases S)

  const int TB = 256;
  dim3 b(TB);
  const int gE2    = (2*EE + TB - 1)/TB;
  const int gBC    = (2*EE + 4095)/4096;
  const int gND    = (NN*DD + TB - 1)/TB;
  const int gND2   = (NN*64 + TB - 1)/TB;
  const int gNodes = (NN + 3)/4;
  const int gMG    = (NN + 63)/64;        // mgemm: 64-row tiles

  prep_all<<<258, b, 0, stream>>>(gat_W, Wk, Wv, Wo, injW, WT8, Wq, bq, a_rel, WQT, bqt,
                                  z_h, fW1, fb1, fW2, fb2, fgb);

  // joint CSR via bucket counting sort
  hipMemsetAsync(bcnt, 0, (NBUCK+4)*sizeof(int), stream);   // bcnt + bnctr
  bucket_count<<<gBC, b, 0, stream>>>(ei0+EE, ei1+EE, bcnt);
  bucket_scan<<<1, 256, 0, stream>>>(bcnt, bbase, bcur);
  fill_bucket<<<gE2, b, 0, stream>>>(ei0, ei1, bcur, EB);
  fill_place<<<NBUCK, b, 0, stream>>>(EB, bbase, jrs, es);

  // ---- 2 hetero-GAT layers ----
  const float* xin = x_cell;
  for(int c=0;c<2;++c){
    MJobs gj{};
    for(int t=0;t<2;++t){
      gj.j[t].WT   = WT8 + (size_t)(c*2+t)*16384;
      gj.j[t].bias = nullptr;
      gj.j[t].as_  = gat_as + (size_t)(c*2+t)*HH*DHH;
      gj.j[t].ad_  = gat_ad + (size_t)(c*2+t)*HH*DHH;
      gj.j[t].Cv   = t? (void*)XP1 : (void*)XP0;
      gj.j[t].att_t = t;
      gj.j[t].sel  = 1;
    }
    mgemmM<<<gMG, b, 0, stream>>>(xin, gj, 2, als8, ald8, NN);
    gat_gather3<<<gNodes, b, 0, stream>>>(XP0, XP1, als8, ald8, jrs, es,
        gat_b + (size_t)(c*2+0)*DD, gat_b + (size_t)(c*2+1)*DD, A);
    bn_stats_fused<<<NBLK, b, 0, stream>>>(A, bnpart, bn_g + (size_t)c*DD, bn_b + (size_t)c*DD, bnstat, bnctr);
    bn_apply_lrelu<<<gND2, b, 0, stream>>>(xin, A, bnstat, X2);   // x1 / x2
    xin = X2;
  }
  float* x2 = X2;

  // ---- HGT ----
  {
    MJobs hj{};
    hj.j[0] = { WQT,                   bqt,       nullptr, nullptr, (void*)QT,          0, 1 };
    hj.j[1] = { WQT + 16384,           bqt + 128, nullptr, nullptr, (void*)(QT + SLOT), 0, 1 };
    hj.j[2] = { WT8 + (size_t)4*16384, bk,        nullptr, nullptr, (void*)KV,          0, 2 };
    hj.j[3] = { WT8 + (size_t)5*16384, bv,        nullptr, nullptr, (void*)KV,          0, 3 };
    mgemmM<<<gMG, b, 0, stream>>>(x2, hj, 4, nullptr, nullptr, NN);
  }
  hgt_merged2<<<gNodes, b, 0, stream>>>(QT, KV, jrs, es, p_rel, S);
  mtransform_kernel<<<gND, b, 0, stream>>>(S, m_rel, MT);   // gelu(M0^T Sv0 + M1^T Sv1) -> bf16
  mgemm<MM_ABF16|MM_BIAS|MM_SKIP><<<gMG, b, 0, stream>>>(MT, WT8 + (size_t)6*16384, bo,
      x2, nullptr, skip, (float*)d_out, NN);
  bn_stats_fused<<<NBLK, b, 0, stream>>>((float*)d_out, bnpart, bn_g + 2*DD, bn_b + 2*DD, bnstat, bnctr);
  bn_apply_lrelu<<<gND2, b, 0, stream>>>(x2, (float*)d_out, bnstat, (float*)d_out);  // x3c in place
  mgemm<MM_BIAS|MM_FILM><<<gMG, b, 0, stream>>>(x_emb, WT8 + (size_t)7*16384, injb,
      (float*)d_out, fgb, nullptr, (float*)d_out, NN);
}

// Round 13
// 668.425 us; speedup vs baseline: 2.4444x; 2.4444x over previous
//
#include <hip/hip_runtime.h>
#include <math.h>

#define NN 50000
#define DD 128
#define HH 4
#define DHH 32
#define EE 600000
#define N2 (2*NN)
#define NBLK 256
#define NBUCK ((N2 + 511)/512)   // 196 buckets of 512 joint-nodes

typedef unsigned short u16;
typedef unsigned int   u32;
typedef unsigned char  u8;
using short8 = __attribute__((ext_vector_type(8))) short;   // 8 bf16 = 4 VGPRs (MFMA A/B frag)
using f32x4  = __attribute__((ext_vector_type(4))) float;   // MFMA C/D frag
using f32x2  = __attribute__((ext_vector_type(2))) float;

#define LOG2E 1.44269504f

__device__ __forceinline__ float lrelu(float v){ return v > 0.f ? v : 0.2f*v; }
__device__ __forceinline__ float gelu_exact(float x){ return 0.5f*x*(1.f+erff(x*0.70710678118654752f)); }
__device__ __forceinline__ u16 f2bf(float f){
  u32 u = __float_as_uint(f);
  u32 r = (u + 0x7fffu + ((u>>16)&1u)) >> 16;
  return (u16)r;
}
__device__ __forceinline__ u32 pack2bf(float a, float b){ return (u32)f2bf(a) | ((u32)f2bf(b)<<16); }
__device__ __forceinline__ float bflo(u32 u){ return __uint_as_float(u<<16); }
__device__ __forceinline__ float bfhi(u32 u){ return __uint_as_float(u & 0xffff0000u); }

// ---------------- fused prep: weights transpose+cast | fold_qA | film ----------------
__global__ __launch_bounds__(256) void prep_all(
    const float* __restrict__ gat_W, const float* __restrict__ Wk, const float* __restrict__ Wv,
    const float* __restrict__ Wo, const float* __restrict__ injW, u16* __restrict__ WT,
    const float* __restrict__ Wq, const float* __restrict__ bq, const float* __restrict__ a_rel,
    u16* __restrict__ wqtT, float* __restrict__ bqt,
    const float* __restrict__ z, const float* __restrict__ fW1, const float* __restrict__ fb1,
    const float* __restrict__ fW2, const float* __restrict__ fb2, float* __restrict__ gb){
  __shared__ float t[32][33];
  __shared__ float hsh[256];
  const int bid = blockIdx.x;
  if(bid < 128){
    const int m = bid >> 4, tile = bid & 15, tr = tile>>2, tc = tile&3;
    const float* src = (m<4) ? (gat_W + (size_t)m*16384) : (m==4? Wk : m==5? Wv : m==6? Wo : injW);
    const int lr = threadIdx.x>>5, lc = threadIdx.x&31;
    #pragma unroll
    for(int p=0;p<4;++p) t[lr+p*8][lc] = src[(size_t)(tr*32+lr+p*8)*128 + tc*32+lc];
    __syncthreads();
    #pragma unroll
    for(int p=0;p<4;++p)
      WT[(size_t)m*16384 + (size_t)(tc*32+lr+p*8)*128 + tr*32+lc] = f2bf(t[lc][lr+p*8]);
  } else if(bid < 257){
    int idx = (bid-128)*256 + threadIdx.x;
    if(idx < 2*128*129){
      int tt = idx / (128*129);
      int r = idx % (128*129);
      int f = r / 129, c = r % 129;
      int h = f>>5, m = f&31;
      const float* srcp = (c<128) ? (Wq + (size_t)c*128 + h*DHH) : (bq + h*DHH);
      const float* arow = a_rel + (((size_t)(tt*HH+h)*DHH)+m)*DHH;
      float s=0.f;
      #pragma unroll
      for(int e=0;e<DHH;++e) s = fmaf(srcp[e], arow[e], s);
      if(c<128) wqtT[(size_t)tt*16384 + (size_t)f*128 + c] = f2bf(s);
      else      bqt[tt*128 + f] = s;
    }
  } else {
    int j = threadIdx.x;
    float acc = fb1[j];
    for(int d=0; d<DD; ++d) acc = fmaf(z[d], fW1[d*256+j], acc);
    hsh[j] = gelu_exact(acc);
    __syncthreads();
    float acc2 = fb2[j];
    for(int k=0;k<256;++k) acc2 = fmaf(hsh[k], fW2[k*256+j], acc2);
    gb[j] = acc2;
  }
}

// ---------------- CSR build via bucket counting sort ----------------
// 1) bucket histogram (LDS-aggregated)
__global__ __launch_bounds__(256) void bucket_count(const int* __restrict__ d0, const int* __restrict__ d1,
                                                    int* __restrict__ bcnt){
  __shared__ int h[NBUCK];
  for(int i=threadIdx.x;i<NBUCK;i+=256) h[i]=0;
  __syncthreads();
  const int e0 = blockIdx.x*4096 + threadIdx.x;
  #pragma unroll
  for(int j=0;j<16;++j){
    int e = e0 + j*256;
    if(e < EE)           atomicAdd(&h[d0[e]>>9], 1);
    else if(e < 2*EE)    atomicAdd(&h[(NN + d1[e-EE])>>9], 1);
  }
  __syncthreads();
  for(int i=threadIdx.x;i<NBUCK;i+=256){ int v=h[i]; if(v) atomicAdd(&bcnt[i], v); }
}

// 2) scan bucket counts -> bbase/bcur
__global__ void bucket_scan(const int* __restrict__ bcnt, int* __restrict__ bbase, int* __restrict__ bcur){
  __shared__ int sh[256];
  int t=threadIdx.x;
  int v = (t<NBUCK)? bcnt[t] : 0;
  sh[t]=v; __syncthreads();
  for(int off=1;off<256;off<<=1){
    int u=(t>=off)?sh[t-off]:0; __syncthreads();
    sh[t]+=u; __syncthreads();
  }
  if(t<NBUCK){ bbase[t]=sh[t]-v; bcur[t]=sh[t]-v; }
  if(t==0) bbase[NBUCK] = 2*EE;
}

// 3) block-aggregated scatter: LDS histogram -> one global atomic per (block,bucket) -> place
__global__ __launch_bounds__(256) void fill_bucket(const int* __restrict__ ei0, const int* __restrict__ ei1,
                                                   int* __restrict__ bcur, u32* __restrict__ eb){
  __shared__ int h[NBUCK];     // counts, then local cursors
  __shared__ int ofs[NBUCK];   // reserved global base per bucket
  for(int i=threadIdx.x;i<NBUCK;i+=256) h[i]=0;
  __syncthreads();
  const int e0 = blockIdx.x*4096 + threadIdx.x;
  int bs[16]; u32 pk[16];
  #pragma unroll
  for(int j=0;j<16;++j){
    int e = e0 + j*256;
    int d = -1, src = 0;
    if(e < EE){ d = ei0[EE+e]; src = ei0[e]; }
    else if(e < 2*EE){ int i=e-EE; d = NN + ei1[EE+i]; src = ei1[i]; }
    if(d >= 0){
      int b = d>>9;
      bs[j] = b;
      pk[j] = ((u32)(d & 511)<<16) | (u32)src;
      atomicAdd(&h[b], 1);
    } else bs[j] = -1;
  }
  __syncthreads();
  for(int i=threadIdx.x;i<NBUCK;i+=256){
    int c = h[i];
    if(c) ofs[i] = atomicAdd(&bcur[i], c);
  }
  __syncthreads();
  for(int i=threadIdx.x;i<NBUCK;i+=256) h[i]=0;   // reuse as local cursor
  __syncthreads();
  #pragma unroll
  for(int j=0;j<16;++j){
    if(bs[j] >= 0){
      int loc = atomicAdd(&h[bs[j]], 1);
      eb[ofs[bs[j]] + loc] = pk[j];
    }
  }
}

// 4) per-bucket: node histogram + scan -> jrs, then place edges into es
__global__ __launch_bounds__(256) void fill_place(const u32* __restrict__ eb, const int* __restrict__ bbase,
                                                  int* __restrict__ jrs, u16* __restrict__ es){
  const int b = blockIdx.x;
  const int nb0 = b*512;
  const int nloc = min(512, N2-nb0);
  const int base = bbase[b], end = bbase[b+1];
  __shared__ int hist[512];
  __shared__ int psum[256];
  const int t = threadIdx.x;
  hist[t]=0; hist[t+256]=0;
  __syncthreads();
  for(int p=base+t; p<end; p+=256) atomicAdd(&hist[eb[p]>>16], 1);
  __syncthreads();
  const int c0 = hist[2*t], c1 = hist[2*t+1];
  const int pair = c0+c1;
  psum[t]=pair; __syncthreads();
  for(int off=1;off<256;off<<=1){
    int u=(t>=off)?psum[t-off]:0; __syncthreads();
    psum[t]+=u; __syncthreads();
  }
  const int ex = base + psum[t]-pair;   // global start of node 2t
  if(2*t   < nloc) jrs[nb0+2*t]   = ex;
  if(2*t+1 < nloc) jrs[nb0+2*t+1] = ex+c0;
  __syncthreads();
  hist[2*t]=ex; hist[2*t+1]=ex+c0;      // reuse as cursors
  __syncthreads();
  for(int p=base+t; p<end; p+=256){
    u32 w = eb[p];
    int pos = atomicAdd(&hist[w>>16], 1);
    es[pos] = (u16)(w & 0xffffu);
  }
  if(b==0 && t==0) jrs[N2] = 2*EE;
}

// ---------------- MFMA GEMM ----------------
constexpr int MM_BIAS  = 1;
constexpr int MM_FILM  = 2;   // o += base[row,c]; o = fgb[c]*o + fgb[128+c]
constexpr int MM_SKIP  = 4;   // o = sk*o + (1-sk)*base[row,c]
constexpr int MM_ABF16 = 64;  // A input is bf16

#define SWZ(row, byte) ((byte) ^ (((row)&7)<<4))

template<int MODE>
__device__ __forceinline__ void mgemm_core(const void* Av, const u16* WT, int row0, int n,
                                           u16* Al, u16* Wl, f32x4 (&acc)[8]){
  const int tid = threadIdx.x;
  if(MODE & MM_ABF16){
    const uint2* Ag = (const uint2*)((const u16*)Av + (size_t)row0*128);
    const int maxv = (min(64, n-row0))*32;
    #pragma unroll
    for(int j=0;j<8;++j){
      int v = tid + j*256;
      uint2 st = make_uint2(0u,0u);
      if(v < maxv) st = Ag[v];
      int row = v>>5, cb = (v&31)*8;
      *(uint2*)((char*)Al + row*256 + SWZ(row, cb)) = st;
    }
  } else {
    const float4* Ag = (const float4*)((const float*)Av + (size_t)row0*128);
    const int maxv = (min(64, n-row0))*32;
    #pragma unroll
    for(int j=0;j<8;++j){
      int v = tid + j*256;
      float4 val = make_float4(0.f,0.f,0.f,0.f);
      if(v < maxv) val = Ag[v];
      int row = v>>5, cb = (v&31)*8;
      uint2 st; st.x = pack2bf(val.x, val.y); st.y = pack2bf(val.z, val.w);
      *(uint2*)((char*)Al + row*256 + SWZ(row, cb)) = st;
    }
  }
  {
    const u32* Wg = (const u32*)WT;
    #pragma unroll
    for(int j=0;j<32;++j){
      int v = tid + j*256;
      u32 w = Wg[v];
      int row = v>>6, cb = (v&63)*4;
      *(u32*)((char*)Wl + row*256 + SWZ(row, cb)) = w;
    }
  }
  __syncthreads();
  const int lane = tid & 63;
  const int wv   = tid >> 6;
  const int r16  = lane & 15;
  const int kg   = lane >> 4;
  #pragma unroll
  for(int nn=0;nn<8;++nn) acc[nn] = (f32x4){0.f,0.f,0.f,0.f};
  #pragma unroll
  for(int s=0;s<4;++s){
    const int arow = wv*16 + r16;
    const int kb = s*64 + kg*16;
    short8 af = *(const short8*)((const char*)Al + arow*256 + SWZ(arow, kb));
    #pragma unroll
    for(int nn=0;nn<8;++nn){
      const int brow = nn*16 + r16;
      short8 bf = *(const short8*)((const char*)Wl + brow*256 + SWZ(brow, kb));
      acc[nn] = __builtin_amdgcn_mfma_f32_16x16x32_bf16(af, bf, acc[nn], 0, 0, 0);
    }
  }
}

// single-job mgemm (f32 out) for Wo / inj epilogues
template<int MODE>
__global__ __launch_bounds__(256) void mgemm(const void* __restrict__ Av, const u16* __restrict__ WT,
    const float* __restrict__ bias, const float* __restrict__ base, const float* __restrict__ fgb,
    const float* __restrict__ skipv, float* __restrict__ C, int n){
  __shared__ u16 Al[64*128];
  __shared__ u16 Wl[128*128];
  const int row0 = blockIdx.x*64;
  f32x4 acc[8];
  mgemm_core<MODE>(Av, WT, row0, n, Al, Wl, acc);
  const int lane = threadIdx.x & 63;
  const int wv   = threadIdx.x >> 6;
  const int r16  = lane & 15;
  const int kg   = lane >> 4;
  float bvals[8];
  if(MODE & MM_BIAS){
    #pragma unroll
    for(int nn=0;nn<8;++nn) bvals[nn] = bias[nn*16+r16];
  }
  float sk = 0.f;
  if(MODE & MM_SKIP) sk = 1.f/(1.f+__expf(-skipv[0]));
  #pragma unroll
  for(int i=0;i<4;++i){
    const int row = row0 + wv*16 + kg*4 + i;
    if(row >= n) continue;
    #pragma unroll
    for(int nn=0;nn<8;++nn){
      const int col = nn*16 + r16;
      float o = acc[nn][i];
      if(MODE & MM_BIAS) o += bvals[nn];
      if(MODE & MM_SKIP)
        o = sk*o + (1.f-sk)*base[(size_t)row*128 + col];
      if(MODE & MM_FILM){
        o += base[(size_t)row*128 + col];
        o = fgb[col]*o + fgb[128+col];
      }
      C[(size_t)row*128 + col] = o;
    }
  }
}

// multi-job mgemm: stages A ONCE, loops jobs. sel: 1 = bf16 out, 2 = KV k fp8, 3 = KV v fp8
struct MJob {
  const u16* WT;
  const float* bias;   // nullptr = none
  const float* as_;    // nullptr = no ATT epilogue
  const float* ad_;
  void* Cv;
  int att_t;
  int sel;
};
struct MJobs { MJob j[4]; };

__global__ __launch_bounds__(256) void mgemmM(const float* __restrict__ Av, MJobs jobs, int njobs,
    float* __restrict__ als8, float* __restrict__ ald8, int n){
  __shared__ u16 Al[64*128];
  __shared__ u16 Wl[128*128];
  const int tid = threadIdx.x;
  const int row0 = blockIdx.x*64;
  { // stage A once (f32 -> bf16)
    const float4* Ag = (const float4*)(Av + (size_t)row0*128);
    const int maxv = (min(64, n-row0))*32;
    #pragma unroll
    for(int j=0;j<8;++j){
      int v = tid + j*256;
      float4 val = make_float4(0.f,0.f,0.f,0.f);
      if(v < maxv) val = Ag[v];
      int row = v>>5, cb = (v&31)*8;
      uint2 st; st.x = pack2bf(val.x, val.y); st.y = pack2bf(val.z, val.w);
      *(uint2*)((char*)Al + row*256 + SWZ(row, cb)) = st;
    }
  }
  const int lane = tid & 63;
  const int wv   = tid >> 6;
  const int r16  = lane & 15;
  const int kg   = lane >> 4;
  for(int jj=0; jj<njobs; ++jj){
    const MJob job = jobs.j[jj];
    {
      const u32* Wg = (const u32*)job.WT;
      #pragma unroll
      for(int j=0;j<32;++j){
        int v = tid + j*256;
        u32 w = Wg[v];
        int row = v>>6, cb = (v&63)*4;
        *(u32*)((char*)Wl + row*256 + SWZ(row, cb)) = w;
      }
    }
    __syncthreads();
    f32x4 acc[8];
    #pragma unroll
    for(int nn=0;nn<8;++nn) acc[nn] = (f32x4){0.f,0.f,0.f,0.f};
    #pragma unroll
    for(int s=0;s<4;++s){
      const int arow = wv*16 + r16;
      const int kb = s*64 + kg*16;
      short8 af = *(const short8*)((const char*)Al + arow*256 + SWZ(arow, kb));
      #pragma unroll
      for(int nn=0;nn<8;++nn){
        const int brow = nn*16 + r16;
        short8 bf = *(const short8*)((const char*)Wl + brow*256 + SWZ(brow, kb));
        acc[nn] = __builtin_amdgcn_mfma_f32_16x16x32_bf16(af, bf, acc[nn], 0, 0, 0);
      }
    }
    if(job.as_){
      float asv[8], adv[8];
      #pragma unroll
      for(int nn=0;nn<8;++nn){ asv[nn]=job.as_[nn*16+r16]; adv[nn]=job.ad_[nn*16+r16]; }
      #pragma unroll
      for(int i=0;i<4;++i){
        const int row = row0 + wv*16 + kg*4 + i;
        #pragma unroll
        for(int h=0;h<4;++h){
          float ps = asv[2*h]*acc[2*h][i] + asv[2*h+1]*acc[2*h+1][i];
          float pd = adv[2*h]*acc[2*h][i] + adv[2*h+1]*acc[2*h+1][i];
          ps += __shfl_xor(ps,1); ps += __shfl_xor(ps,2); ps += __shfl_xor(ps,4); ps += __shfl_xor(ps,8);
          pd += __shfl_xor(pd,1); pd += __shfl_xor(pd,2); pd += __shfl_xor(pd,4); pd += __shfl_xor(pd,8);
          if(row < n && r16 == 0){
            als8[(size_t)row*8 + 2*h + job.att_t] = ps;
            ald8[(size_t)row*8 + 2*h + job.att_t] = pd;
          }
        }
      }
    }
    float bvals[8];
    #pragma unroll
    for(int nn=0;nn<8;++nn) bvals[nn] = job.bias ? job.bias[nn*16+r16] : 0.f;
    #pragma unroll
    for(int i=0;i<4;++i){
      const int row = row0 + wv*16 + kg*4 + i;
      if(row >= n) continue;
      #pragma unroll
      for(int nn=0;nn<8;++nn){
        const int col = nn*16 + r16;
        float o = acc[nn][i] + bvals[nn];
        if(job.sel == 1){
          ((u16*)job.Cv)[(size_t)row*128 + col] = f2bf(o);
        } else {
          u32 enc = __builtin_amdgcn_cvt_pk_fp8_f32(o, 0.f, 0u, false);
          ((u8*)job.Cv)[(size_t)row*256 + (col>>1)*4 + (col&1) + (job.sel-2)*2] = (u8)(enc & 0xffu);
        }
      }
    }
    __syncthreads();
  }
}

// ---------------- GAT merged gather: both types, per-type xp tables (bf16) ----------------
__global__ __launch_bounds__(256) void gat_gather3(const u16* __restrict__ xp0, const u16* __restrict__ xp1,
    const float* __restrict__ als8, const float* __restrict__ ald8,
    const int* __restrict__ jrs, const u16* __restrict__ es,
    const float* __restrict__ gb0, const float* __restrict__ gb1, float* __restrict__ out){
  const int gid = blockIdx.x*blockDim.x + threadIdx.x;
  const int node = gid >> 6;
  const int lane = threadIdx.x & 63;
  if(node >= NN) return;
  const int h = lane >> 4;
  const int cc = 2*lane;
  float o0 = gb0[cc] + gb1[cc], o1 = gb0[cc+1] + gb1[cc+1];
  #pragma unroll
  for(int t=0;t<2;++t){
    const u16* __restrict__ xp = t ? xp1 : xp0;
    const float aldv = ald8[(size_t)node*8 + 2*h + t];
    const int s0 = jrs[t*NN+node], s1 = jrs[t*NN+node+1];
    float ssum=0.f, a0=0.f, a1=0.f;
    int p = s0;
    for(; p+3<s1; p+=4){
      const int sA = es[p], sB = es[p+1], sC = es[p+2], sD = es[p+3];
      const u32 xA = *(const u32*)&xp[(size_t)sA*DD + cc];
      const u32 xB = *(const u32*)&xp[(size_t)sB*DD + cc];
      const u32 xC = *(const u32*)&xp[(size_t)sC*DD + cc];
      const u32 xD = *(const u32*)&xp[(size_t)sD*DD + cc];
      float lA = als8[(size_t)sA*8 + 2*h + t] + aldv;
      float lB = als8[(size_t)sB*8 + 2*h + t] + aldv;
      float lC = als8[(size_t)sC*8 + 2*h + t] + aldv;
      float lD = als8[(size_t)sD*8 + 2*h + t] + aldv;
      const float eA = exp2f(lA>0.f ? lA*LOG2E : lA*(0.2f*LOG2E));
      const float eB = exp2f(lB>0.f ? lB*LOG2E : lB*(0.2f*LOG2E));
      const float eC = exp2f(lC>0.f ? lC*LOG2E : lC*(0.2f*LOG2E));
      const float eD = exp2f(lD>0.f ? lD*LOG2E : lD*(0.2f*LOG2E));
      ssum += (eA+eB)+(eC+eD);
      a0 = fmaf(eA, bflo(xA), a0); a1 = fmaf(eA, bfhi(xA), a1);
      a0 = fmaf(eB, bflo(xB), a0); a1 = fmaf(eB, bfhi(xB), a1);
      a0 = fmaf(eC, bflo(xC), a0); a1 = fmaf(eC, bfhi(xC), a1);
      a0 = fmaf(eD, bflo(xD), a0); a1 = fmaf(eD, bfhi(xD), a1);
    }
    for(; p<s1; ++p){
      const int sA = es[p];
      const u32 xA = *(const u32*)&xp[(size_t)sA*DD + cc];
      float lA = als8[(size_t)sA*8 + 2*h + t] + aldv;
      const float eA = exp2f(lA>0.f ? lA*LOG2E : lA*(0.2f*LOG2E));
      ssum += eA;
      a0 = fmaf(eA, bflo(xA), a0); a1 = fmaf(eA, bfhi(xA), a1);
    }
    { // self loop (appended in reference)
      float lg = als8[(size_t)node*8 + 2*h + t] + aldv;
      const float ev = exp2f(lg>0.f ? lg*LOG2E : lg*(0.2f*LOG2E));
      ssum += ev;
      const u32 xr = *(const u32*)&xp[(size_t)node*DD + cc];
      a0 = fmaf(ev, bflo(xr), a0); a1 = fmaf(ev, bfhi(xr), a1);
    }
    const float inv = 1.f/ssum;
    o0 = fmaf(a0, inv, o0); o1 = fmaf(a1, inv, o1);
  }
  *(float2*)&out[(size_t)node*DD + cc] = make_float2(o0, o1);
}

// ---------------- BN: stats + fenced last-block finalize (deterministic, parallel tail) ----------------
__global__ __launch_bounds__(256) void bn_stats_fused(const float* __restrict__ X, float* __restrict__ part,
                               const float* __restrict__ gamma, const float* __restrict__ beta,
                               float* __restrict__ stat, int* __restrict__ counter){
  const int f = threadIdx.x & 127, rg = threadIdx.x>>7;
  float s=0.f, s2=0.f;
  for(int r = blockIdx.x*2+rg; r<NN; r += NBLK*2){
    float v = X[(size_t)r*DD+f]; s+=v; s2 = fmaf(v,v,s2);
  }
  __shared__ float ls[256], ls2[256];
  __shared__ int lastsh;
  ls[threadIdx.x]=s; ls2[threadIdx.x]=s2; __syncthreads();
  if(rg==0){
    part[blockIdx.x*256 + f]       = ls[f]+ls[128+f];
    part[blockIdx.x*256 + 128 + f] = ls2[f]+ls2[128+f];
  }
  __threadfence();
  if(threadIdx.x==0) lastsh = (atomicAdd(counter,1) == NBLK-1);
  __syncthreads();
  if(lastsh){
    __threadfence();
    float ss=0.f, ss2=0.f;
    #pragma unroll 8
    for(int bk=rg; bk<NBLK; bk+=2){
      ss  += part[bk*256 + f];
      ss2 += part[bk*256 + 128 + f];
    }
    __syncthreads();
    ls[threadIdx.x]=ss; ls2[threadIdx.x]=ss2;
    __syncthreads();
    if(rg==0){
      float S1 = ls[f]+ls[128+f], S2 = ls2[f]+ls2[128+f];
      float mu = S1/(float)NN;
      float var = S2/(float)NN - mu*mu;
      float rs = rsqrtf(var+1e-5f);
      stat[f]     = gamma[f]*rs;
      stat[128+f] = beta[f] - gamma[f]*rs*mu;
    }
    if(threadIdx.x==0) *counter = 0;
  }
}

// out = lrelu(xprev + A*acc + B)
__global__ void bn_apply_lrelu(const float* __restrict__ xprev, const float* __restrict__ acc,
                               const float* __restrict__ stat, float* __restrict__ out){
  int idx = blockIdx.x*blockDim.x+threadIdx.x;
  if(idx >= NN*64) return;
  int c = (2*idx) & 127;
  float2 x = ((const float2*)xprev)[idx];
  float2 a = ((const float2*)acc)[idx];
  float o0 = lrelu(x.x + fmaf(stat[c],   a.x, stat[128+c]));
  float o1 = lrelu(x.y + fmaf(stat[c+1], a.y, stat[128+c+1]));
  ((float2*)out)[idx] = make_float2(o0,o1);
}

// ---------------- HGT merged edge kernel: qt tables + fp8 interleaved KV ----------------
__global__ __launch_bounds__(256) void hgt_merged2(const u16* __restrict__ qt,
    const u32* __restrict__ kv, const int* __restrict__ jrs, const u16* __restrict__ es,
    const float* __restrict__ p_rel, u16* __restrict__ Sv){
  const int gid = blockIdx.x*blockDim.x + threadIdx.x;
  const int node = gid >> 6;
  const int lane = threadIdx.x & 63;
  if(node >= NN) return;
  const int h = lane >> 4;
  float acc[2][2] = {{0.f,0.f},{0.f,0.f}};
  float ssum = 0.f;
  #pragma unroll
  for(int t=0;t<2;++t){
    const u32 qw = *(const u32*)&qt[(size_t)t*NN*DD + (size_t)node*DD + 2*lane];
    const float q0 = bflo(qw), q1 = bfhi(qw);
    const float scale2 = p_rel[t*HH+h]*(0.17677669529663687f*LOG2E);
    const int s0 = jrs[t*NN+node], s1 = jrs[t*NN+node+1];
    int p = s0;
    for(; p+3<s1; p+=4){
      const int sA = es[p], sB = es[p+1], sC = es[p+2], sD = es[p+3];
      const u32 wA = kv[(size_t)sA*64 + lane];
      const u32 wB = kv[(size_t)sB*64 + lane];
      const u32 wC = kv[(size_t)sC*64 + lane];
      const u32 wD = kv[(size_t)sD*64 + lane];
      f32x2 kA = __builtin_amdgcn_cvt_pk_f32_fp8(wA, false);
      f32x2 kB = __builtin_amdgcn_cvt_pk_f32_fp8(wB, false);
      f32x2 kC = __builtin_amdgcn_cvt_pk_f32_fp8(wC, false);
      f32x2 kD = __builtin_amdgcn_cvt_pk_f32_fp8(wD, false);
      f32x2 vA = __builtin_amdgcn_cvt_pk_f32_fp8(wA, true);
      f32x2 vB = __builtin_amdgcn_cvt_pk_f32_fp8(wB, true);
      f32x2 vC = __builtin_amdgcn_cvt_pk_f32_fp8(wC, true);
      f32x2 vD = __builtin_amdgcn_cvt_pk_f32_fp8(wD, true);
      float pA = q0*kA.x + q1*kA.y;
      float pB = q0*kB.x + q1*kB.y;
      float pC = q0*kC.x + q1*kC.y;
      float pD = q0*kD.x + q1*kD.y;
      pA += __shfl_xor(pA,1); pB += __shfl_xor(pB,1); pC += __shfl_xor(pC,1); pD += __shfl_xor(pD,1);
      pA += __shfl_xor(pA,2); pB += __shfl_xor(pB,2); pC += __shfl_xor(pC,2); pD += __shfl_xor(pD,2);
      pA += __shfl_xor(pA,4); pB += __shfl_xor(pB,4); pC += __shfl_xor(pC,4); pD += __shfl_xor(pD,4);
      pA += __shfl_xor(pA,8); pB += __shfl_xor(pB,8); pC += __shfl_xor(pC,8); pD += __shfl_xor(pD,8);
      const float eA=exp2f(pA*scale2), eB=exp2f(pB*scale2);
      const float eC=exp2f(pC*scale2), eD=exp2f(pD*scale2);
      ssum += (eA+eB)+(eC+eD);
      acc[t][0] = fmaf(eA, vA.x, acc[t][0]); acc[t][1] = fmaf(eA, vA.y, acc[t][1]);
      acc[t][0] = fmaf(eB, vB.x, acc[t][0]); acc[t][1] = fmaf(eB, vB.y, acc[t][1]);
      acc[t][0] = fmaf(eC, vC.x, acc[t][0]); acc[t][1] = fmaf(eC, vC.y, acc[t][1]);
      acc[t][0] = fmaf(eD, vD.x, acc[t][0]); acc[t][1] = fmaf(eD, vD.y, acc[t][1]);
    }
    for(; p<s1; ++p){
      const int sA = es[p];
      const u32 wA = kv[(size_t)sA*64 + lane];
      f32x2 kA = __builtin_amdgcn_cvt_pk_f32_fp8(wA, false);
      f32x2 vA = __builtin_amdgcn_cvt_pk_f32_fp8(wA, true);
      float pA = q0*kA.x + q1*kA.y;
      pA += __shfl_xor(pA,1); pA += __shfl_xor(pA,2); pA += __shfl_xor(pA,4); pA += __shfl_xor(pA,8);
      const float eA = exp2f(pA*scale2);
      ssum += eA;
      acc[t][0] = fmaf(eA, vA.x, acc[t][0]); acc[t][1] = fmaf(eA, vA.y, acc[t][1]);
    }
  }
  const float inv = ssum>0.f ? 1.f/ssum : 0.f;
  ((u32*)&Sv[(size_t)node*256 +       2*lane])[0] = pack2bf(acc[0][0]*inv, acc[0][1]*inv);
  ((u32*)&Sv[(size_t)node*256 + 128 + 2*lane])[0] = pack2bf(acc[1][0]*inv, acc[1][1]*inv);
}

// ---------------- post-aggregation m_rel transform + gelu (bf16 out) ----------------
__global__ __launch_bounds__(256) void mtransform_kernel(const u16* __restrict__ Sv, const float* __restrict__ m_rel,
                                                         u16* __restrict__ out){
  __shared__ float Msh[2*HH*DHH*DHH];   // 32 KB
  for(int i=threadIdx.x;i<2*HH*DHH*DHH;i+=256) Msh[i]=m_rel[i];
  __syncthreads();
  int idx = blockIdx.x*blockDim.x + threadIdx.x;
  if(idx >= NN*DD) return;
  int node = idx>>7, f = idx&127, h = f>>5, e = f&31;
  const u16* s0p = &Sv[(size_t)node*256 + h*DHH];
  const u16* s1p = &Sv[(size_t)node*256 + 128 + h*DHH];
  const float* M0 = &Msh[(0*HH+h)*DHH*DHH + e];
  const float* M1 = &Msh[(1*HH+h)*DHH*DHH + e];
  float s = 0.f;
  #pragma unroll
  for(int d=0; d<DHH; d+=2){
    u32 w0 = *(const u32*)&s0p[d];
    u32 w1 = *(const u32*)&s1p[d];
    s = fmaf(bflo(w0), M0[d*DHH],     s);
    s = fmaf(bfhi(w0), M0[(d+1)*DHH], s);
    s = fmaf(bflo(w1), M1[d*DHH],     s);
    s = fmaf(bfhi(w1), M1[(d+1)*DHH], s);
  }
  out[idx] = f2bf(gelu_exact(s));
}

// ---------------- host ----------------
extern "C" void kernel_launch(void* const* d_in, const int* in_sizes, int n_in,
                              void* d_out, int out_size, void* d_ws, size_t ws_size,
                              hipStream_t stream){
  const float* x_cell = (const float*)d_in[0];
  const float* z_h    = (const float*)d_in[1];
  const float* x_emb  = (const float*)d_in[2];
  const int*   ei0    = (const int*)d_in[3];
  const int*   ei1    = (const int*)d_in[4];
  const float* gat_W  = (const float*)d_in[5];
  const float* gat_as = (const float*)d_in[6];
  const float* gat_ad = (const float*)d_in[7];
  const float* gat_b  = (const float*)d_in[8];
  const float* bn_g   = (const float*)d_in[9];
  const float* bn_b   = (const float*)d_in[10];
  const float* Wk = (const float*)d_in[11];
  const float* bk = (const float*)d_in[12];
  const float* Wq = (const float*)d_in[13];
  const float* bq = (const float*)d_in[14];
  const float* Wv = (const float*)d_in[15];
  const float* bv = (const float*)d_in[16];
  const float* a_rel = (const float*)d_in[17];
  const float* m_rel = (const float*)d_in[18];
  const float* p_rel = (const float*)d_in[19];
  const float* Wo = (const float*)d_in[20];
  const float* bo = (const float*)d_in[21];
  const float* skip = (const float*)d_in[22];
  const float* injW = (const float*)d_in[23];
  const float* injb = (const float*)d_in[24];
  const float* fW1 = (const float*)d_in[25];
  const float* fb1 = (const float*)d_in[26];
  const float* fW2 = (const float*)d_in[27];
  const float* fb2 = (const float*)d_in[28];

  constexpr size_t SLOT = (size_t)NN*DD;   // 6.4M elements
  float* ws = (float*)d_ws;
  float* A    = ws;                       // pre-BN acc / QT tables (bf16 x2) / mtransform bf16 out
  float* X2   = A + SLOT;                 // x1 then x2 (f32)
  float* als8 = X2 + SLOT;                // NN*8  [node][2*h+t]
  float* ald8 = als8 + (size_t)NN*8;      // NN*8
  float* bnpart = ald8 + (size_t)NN*8;    // 256*256
  float* bnstat = bnpart + 256*256;       // 256
  float* fgb    = bnstat + 256;           // 256
  float* bqt    = fgb + 256;              // 2*128
  u16* WT8  = (u16*)(bqt + 2*128);        // 8 * 128*128 bf16 (transposed weights)
  u16* WQT  = WT8 + (size_t)8*16384;      // 2 * 128*128 bf16 (folded q weights, transposed)
  u16* S    = WQT + (size_t)2*16384;      // NN*256 bf16 (HGT Sv) ; eb (u32*2EE) aliases S
  u16* XP0  = S + (size_t)NN*256;         // NN*128 bf16 (xp type0) ; fp8 KV aliases XP0
  u16* XP1  = XP0 + SLOT;                 // NN*128 bf16 (xp type1)
  u16* es   = XP1 + SLOT;                 // 2*EE u16
  int* bcnt = (int*)(es + (size_t)2*EE + 2);  // NBUCK (memset with bnctr)
  int* bnctr= bcnt + NBUCK;               // 4 ints
  int* jrs  = bnctr + 4;                  // N2+1
  int* bbase= jrs + N2 + 2;               // NBUCK+1
  int* bcur = bbase + NBUCK + 2;          // NBUCK
  size_t needed = (size_t)((char*)(bcur + NBUCK + 2) - (char*)d_ws);
  if(ws_size < needed) return;  // insufficient scratch: fail loud (poisoned d_out)

  u16* QT = (u16*)A;            // 2 bf16 qt tables alias the A slot during HGT edge phase
  u16* MT = (u16*)A;            // mtransform bf16 out (QT dead by then)
  u32* KV = (u32*)XP0;          // fp8 interleaved k/v table: NN rows x 64 u32 (12.8 MB)
  u32* EB = (u32*)S;            // bucket-sorted packed edges (4.8 MB, aliases S)

  const int TB = 256;
  dim3 b(TB);
  const int gBC    = (2*EE + 4095)/4096;
  const int gND    = (NN*DD + TB - 1)/TB;
  const int gND2   = (NN*64 + TB - 1)/TB;
  const int gNodes = (NN + 3)/4;
  const int gMG    = (NN + 63)/64;        // mgemm: 64-row tiles

  prep_all<<<258, b, 0, stream>>>(gat_W, Wk, Wv, Wo, injW, WT8, Wq, bq, a_rel, WQT, bqt,
                                  z_h, fW1, fb1, fW2, fb2, fgb);

  // joint CSR via bucket counting sort (block-aggregated reservations)
  hipMemsetAsync(bcnt, 0, (NBUCK+4)*sizeof(int), stream);   // bcnt + bnctr
  bucket_count<<<gBC, b, 0, stream>>>(ei0+EE, ei1+EE, bcnt);
  bucket_scan<<<1, 256, 0, stream>>>(bcnt, bbase, bcur);
  fill_bucket<<<gBC, b, 0, stream>>>(ei0, ei1, bcur, EB);
  fill_place<<<NBUCK, b, 0, stream>>>(EB, bbase, jrs, es);

  // ---- 2 hetero-GAT layers ----
  const float* xin = x_cell;
  for(int c=0;c<2;++c){
    MJobs gj{};
    for(int t=0;t<2;++t){
      gj.j[t].WT   = WT8 + (size_t)(c*2+t)*16384;
      gj.j[t].bias = nullptr;
      gj.j[t].as_  = gat_as + (size_t)(c*2+t)*HH*DHH;
      gj.j[t].ad_  = gat_ad + (size_t)(c*2+t)*HH*DHH;
      gj.j[t].Cv   = t? (void*)XP1 : (void*)XP0;
      gj.j[t].att_t = t;
      gj.j[t].sel  = 1;
    }
    mgemmM<<<gMG, b, 0, stream>>>(xin, gj, 2, als8, ald8, NN);
    gat_gather3<<<gNodes, b, 0, stream>>>(XP0, XP1, als8, ald8, jrs, es,
        gat_b + (size_t)(c*2+0)*DD, gat_b + (size_t)(c*2+1)*DD, A);
    bn_stats_fused<<<NBLK, b, 0, stream>>>(A, bnpart, bn_g + (size_t)c*DD, bn_b + (size_t)c*DD, bnstat, bnctr);
    bn_apply_lrelu<<<gND2, b, 0, stream>>>(xin, A, bnstat, X2);   // x1 / x2
    xin = X2;
  }
  float* x2 = X2;

  // ---- HGT ----
  {
    MJobs hj{};
    hj.j[0] = { WQT,                   bqt,       nullptr, nullptr, (void*)QT,          0, 1 };
    hj.j[1] = { WQT + 16384,           bqt + 128, nullptr, nullptr, (void*)(QT + SLOT), 0, 1 };
    hj.j[2] = { WT8 + (size_t)4*16384, bk,        nullptr, nullptr, (void*)KV,          0, 2 };
    hj.j[3] = { WT8 + (size_t)5*16384, bv,        nullptr, nullptr, (void*)KV,          0, 3 };
    mgemmM<<<gMG, b, 0, stream>>>(x2, hj, 4, nullptr, nullptr, NN);
  }
  hgt_merged2<<<gNodes, b, 0, stream>>>(QT, KV, jrs, es, p_rel, S);
  mtransform_kernel<<<gND, b, 0, stream>>>(S, m_rel, MT);   // gelu(M0^T Sv0 + M1^T Sv1) -> bf16
  mgemm<MM_ABF16|MM_BIAS|MM_SKIP><<<gMG, b, 0, stream>>>(MT, WT8 + (size_t)6*16384, bo,
      x2, nullptr, skip, (float*)d_out, NN);
  bn_stats_fused<<<NBLK, b, 0, stream>>>((float*)d_out, bnpart, bn_g + 2*DD, bn_b + 2*DD, bnstat, bnctr);
  bn_apply_lrelu<<<gND2, b, 0, stream>>>(x2, (float*)d_out, bnstat, (float*)d_out);  // x3c in place
  mgemm<MM_BIAS|MM_FILM><<<gMG, b, 0, stream>>>(x_emb, WT8 + (size_t)7*16384, injb,
      (float*)d_out, fgb, nullptr, (float*)d_out, NN);
}

// Round 15
// 668.142 us; speedup vs baseline: 2.4454x; 1.0004x over previous
//
#include <hip/hip_runtime.h>
#include <math.h>

#define NN 50000
#define DD 128
#define HH 4
#define DHH 32
#define EE 600000
#define N2 (2*NN)
#define NBLK 256
#define NBUCK ((N2 + 511)/512)   // 196 buckets of 512 joint-nodes

typedef unsigned short u16;
typedef unsigned int   u32;
typedef unsigned char  u8;
using short8 = __attribute__((ext_vector_type(8))) short;   // 8 bf16 = 4 VGPRs (MFMA A/B frag)
using f32x4  = __attribute__((ext_vector_type(4))) float;   // MFMA C/D frag
using f32x2  = __attribute__((ext_vector_type(2))) float;

#define LOG2E 1.44269504f

__device__ __forceinline__ float lrelu(float v){ return v > 0.f ? v : 0.2f*v; }
__device__ __forceinline__ float gelu_exact(float x){ return 0.5f*x*(1.f+erff(x*0.70710678118654752f)); }
__device__ __forceinline__ u16 f2bf(float f){
  u32 u = __float_as_uint(f);
  u32 r = (u + 0x7fffu + ((u>>16)&1u)) >> 16;
  return (u16)r;
}
__device__ __forceinline__ u32 pack2bf(float a, float b){ return (u32)f2bf(a) | ((u32)f2bf(b)<<16); }
__device__ __forceinline__ float bflo(u32 u){ return __uint_as_float(u<<16); }
__device__ __forceinline__ float bfhi(u32 u){ return __uint_as_float(u & 0xffff0000u); }

// ---------------- fused prep: weights transpose+cast | fold_qA | film ----------------
__global__ __launch_bounds__(256) void prep_all(
    const float* __restrict__ gat_W, const float* __restrict__ Wk, const float* __restrict__ Wv,
    const float* __restrict__ Wo, const float* __restrict__ injW, u16* __restrict__ WT,
    const float* __restrict__ Wq, const float* __restrict__ bq, const float* __restrict__ a_rel,
    u16* __restrict__ wqtT, float* __restrict__ bqt,
    const float* __restrict__ z, const float* __restrict__ fW1, const float* __restrict__ fb1,
    const float* __restrict__ fW2, const float* __restrict__ fb2, float* __restrict__ gb){
  __shared__ float t[32][33];
  __shared__ float hsh[256];
  const int bid = blockIdx.x;
  if(bid < 128){
    const int m = bid >> 4, tile = bid & 15, tr = tile>>2, tc = tile&3;
    const float* src = (m<4) ? (gat_W + (size_t)m*16384) : (m==4? Wk : m==5? Wv : m==6? Wo : injW);
    const int lr = threadIdx.x>>5, lc = threadIdx.x&31;
    #pragma unroll
    for(int p=0;p<4;++p) t[lr+p*8][lc] = src[(size_t)(tr*32+lr+p*8)*128 + tc*32+lc];
    __syncthreads();
    #pragma unroll
    for(int p=0;p<4;++p)
      WT[(size_t)m*16384 + (size_t)(tc*32+lr+p*8)*128 + tr*32+lc] = f2bf(t[lc][lr+p*8]);
  } else if(bid < 257){
    int idx = (bid-128)*256 + threadIdx.x;
    if(idx < 2*128*129){
      int tt = idx / (128*129);
      int r = idx % (128*129);
      int f = r / 129, c = r % 129;
      int h = f>>5, m = f&31;
      const float* srcp = (c<128) ? (Wq + (size_t)c*128 + h*DHH) : (bq + h*DHH);
      const float* arow = a_rel + (((size_t)(tt*HH+h)*DHH)+m)*DHH;
      float s=0.f;
      #pragma unroll
      for(int e=0;e<DHH;++e) s = fmaf(srcp[e], arow[e], s);
      if(c<128) wqtT[(size_t)tt*16384 + (size_t)f*128 + c] = f2bf(s);
      else      bqt[tt*128 + f] = s;
    }
  } else {
    int j = threadIdx.x;
    float acc = fb1[j];
    for(int d=0; d<DD; ++d) acc = fmaf(z[d], fW1[d*256+j], acc);
    hsh[j] = gelu_exact(acc);
    __syncthreads();
    float acc2 = fb2[j];
    for(int k=0;k<256;++k) acc2 = fmaf(hsh[k], fW2[k*256+j], acc2);
    gb[j] = acc2;
  }
}

// ---------------- CSR build via bucket counting sort ----------------
__global__ __launch_bounds__(256) void bucket_count(const int* __restrict__ d0, const int* __restrict__ d1,
                                                    int* __restrict__ bcnt){
  __shared__ int h[NBUCK];
  for(int i=threadIdx.x;i<NBUCK;i+=256) h[i]=0;
  __syncthreads();
  const int e0 = blockIdx.x*4096 + threadIdx.x;
  #pragma unroll
  for(int j=0;j<16;++j){
    int e = e0 + j*256;
    if(e < EE)           atomicAdd(&h[d0[e]>>9], 1);
    else if(e < 2*EE)    atomicAdd(&h[(NN + d1[e-EE])>>9], 1);
  }
  __syncthreads();
  for(int i=threadIdx.x;i<NBUCK;i+=256){ int v=h[i]; if(v) atomicAdd(&bcnt[i], v); }
}

__global__ void bucket_scan(const int* __restrict__ bcnt, int* __restrict__ bbase, int* __restrict__ bcur){
  __shared__ int sh[256];
  int t=threadIdx.x;
  int v = (t<NBUCK)? bcnt[t] : 0;
  sh[t]=v; __syncthreads();
  for(int off=1;off<256;off<<=1){
    int u=(t>=off)?sh[t-off]:0; __syncthreads();
    sh[t]+=u; __syncthreads();
  }
  if(t<NBUCK){ bbase[t]=sh[t]-v; bcur[t]=sh[t]-v; }
  if(t==0) bbase[NBUCK] = 2*EE;
}

__global__ __launch_bounds__(256) void fill_bucket(const int* __restrict__ ei0, const int* __restrict__ ei1,
                                                   int* __restrict__ bcur, u32* __restrict__ eb){
  __shared__ int h[NBUCK];     // counts, then local cursors
  __shared__ int ofs[NBUCK];   // reserved global base per bucket
  for(int i=threadIdx.x;i<NBUCK;i+=256) h[i]=0;
  __syncthreads();
  const int e0 = blockIdx.x*4096 + threadIdx.x;
  int bs[16]; u32 pk[16];
  #pragma unroll
  for(int j=0;j<16;++j){
    int e = e0 + j*256;
    int d = -1, src = 0;
    if(e < EE){ d = ei0[EE+e]; src = ei0[e]; }
    else if(e < 2*EE){ int i=e-EE; d = NN + ei1[EE+i]; src = ei1[i]; }
    if(d >= 0){
      int b = d>>9;
      bs[j] = b;
      pk[j] = ((u32)(d & 511)<<16) | (u32)src;
      atomicAdd(&h[b], 1);
    } else bs[j] = -1;
  }
  __syncthreads();
  for(int i=threadIdx.x;i<NBUCK;i+=256){
    int c = h[i];
    if(c) ofs[i] = atomicAdd(&bcur[i], c);
  }
  __syncthreads();
  for(int i=threadIdx.x;i<NBUCK;i+=256) h[i]=0;   // reuse as local cursor
  __syncthreads();
  #pragma unroll
  for(int j=0;j<16;++j){
    if(bs[j] >= 0){
      int loc = atomicAdd(&h[bs[j]], 1);
      eb[ofs[bs[j]] + loc] = pk[j];
    }
  }
}

__global__ __launch_bounds__(256) void fill_place(const u32* __restrict__ eb, const int* __restrict__ bbase,
                                                  int* __restrict__ jrs, u16* __restrict__ es){
  const int b = blockIdx.x;
  const int nb0 = b*512;
  const int nloc = min(512, N2-nb0);
  const int base = bbase[b], end = bbase[b+1];
  __shared__ int hist[512];
  __shared__ int psum[256];
  const int t = threadIdx.x;
  hist[t]=0; hist[t+256]=0;
  __syncthreads();
  for(int p=base+t; p<end; p+=256) atomicAdd(&hist[eb[p]>>16], 1);
  __syncthreads();
  const int c0 = hist[2*t], c1 = hist[2*t+1];
  const int pair = c0+c1;
  psum[t]=pair; __syncthreads();
  for(int off=1;off<256;off<<=1){
    int u=(t>=off)?psum[t-off]:0; __syncthreads();
    psum[t]+=u; __syncthreads();
  }
  const int ex = base + psum[t]-pair;   // global start of node 2t
  if(2*t   < nloc) jrs[nb0+2*t]   = ex;
  if(2*t+1 < nloc) jrs[nb0+2*t+1] = ex+c0;
  __syncthreads();
  hist[2*t]=ex; hist[2*t+1]=ex+c0;      // reuse as cursors
  __syncthreads();
  for(int p=base+t; p<end; p+=256){
    u32 w = eb[p];
    int pos = atomicAdd(&hist[w>>16], 1);
    es[pos] = (u16)(w & 0xffffu);
  }
  if(b==0 && t==0) jrs[N2] = 2*EE;
}

// ---------------- MFMA GEMM ----------------
constexpr int MM_BIAS  = 1;
constexpr int MM_FILM  = 2;   // o += base[row,c]; o = fgb[c]*o + fgb[128+c]
constexpr int MM_SKIP  = 4;   // o = sk*o + (1-sk)*base[row,c]
constexpr int MM_ABF16 = 64;  // A input is bf16

#define SWZ(row, byte) ((byte) ^ (((row)&7)<<4))

template<int MODE>
__device__ __forceinline__ void mgemm_core(const void* Av, const u16* WT, int row0, int n,
                                           u16* Al, u16* Wl, f32x4 (&acc)[8]){
  const int tid = threadIdx.x;
  if(MODE & MM_ABF16){
    const uint2* Ag = (const uint2*)((const u16*)Av + (size_t)row0*128);
    const int maxv = (min(64, n-row0))*32;
    #pragma unroll
    for(int j=0;j<8;++j){
      int v = tid + j*256;
      uint2 st = make_uint2(0u,0u);
      if(v < maxv) st = Ag[v];
      int row = v>>5, cb = (v&31)*8;
      *(uint2*)((char*)Al + row*256 + SWZ(row, cb)) = st;
    }
  } else {
    const float4* Ag = (const float4*)((const float*)Av + (size_t)row0*128);
    const int maxv = (min(64, n-row0))*32;
    #pragma unroll
    for(int j=0;j<8;++j){
      int v = tid + j*256;
      float4 val = make_float4(0.f,0.f,0.f,0.f);
      if(v < maxv) val = Ag[v];
      int row = v>>5, cb = (v&31)*8;
      uint2 st; st.x = pack2bf(val.x, val.y); st.y = pack2bf(val.z, val.w);
      *(uint2*)((char*)Al + row*256 + SWZ(row, cb)) = st;
    }
  }
  {
    const u32* Wg = (const u32*)WT;
    #pragma unroll
    for(int j=0;j<32;++j){
      int v = tid + j*256;
      u32 w = Wg[v];
      int row = v>>6, cb = (v&63)*4;
      *(u32*)((char*)Wl + row*256 + SWZ(row, cb)) = w;
    }
  }
  __syncthreads();
  const int lane = tid & 63;
  const int wv   = tid >> 6;
  const int r16  = lane & 15;
  const int kg   = lane >> 4;
  #pragma unroll
  for(int nn=0;nn<8;++nn) acc[nn] = (f32x4){0.f,0.f,0.f,0.f};
  #pragma unroll
  for(int s=0;s<4;++s){
    const int arow = wv*16 + r16;
    const int kb = s*64 + kg*16;
    short8 af = *(const short8*)((const char*)Al + arow*256 + SWZ(arow, kb));
    #pragma unroll
    for(int nn=0;nn<8;++nn){
      const int brow = nn*16 + r16;
      short8 bf = *(const short8*)((const char*)Wl + brow*256 + SWZ(brow, kb));
      acc[nn] = __builtin_amdgcn_mfma_f32_16x16x32_bf16(af, bf, acc[nn], 0, 0, 0);
    }
  }
}

// single-job mgemm (f32 out) for Wo / inj epilogues
template<int MODE>
__global__ __launch_bounds__(256) void mgemm(const void* __restrict__ Av, const u16* __restrict__ WT,
    const float* __restrict__ bias, const float* __restrict__ base, const float* __restrict__ fgb,
    const float* __restrict__ skipv, float* __restrict__ C, int n){
  __shared__ u16 Al[64*128];
  __shared__ u16 Wl[128*128];
  const int row0 = blockIdx.x*64;
  f32x4 acc[8];
  mgemm_core<MODE>(Av, WT, row0, n, Al, Wl, acc);
  const int lane = threadIdx.x & 63;
  const int wv   = threadIdx.x >> 6;
  const int r16  = lane & 15;
  const int kg   = lane >> 4;
  float bvals[8];
  if(MODE & MM_BIAS){
    #pragma unroll
    for(int nn=0;nn<8;++nn) bvals[nn] = bias[nn*16+r16];
  }
  float sk = 0.f;
  if(MODE & MM_SKIP) sk = 1.f/(1.f+__expf(-skipv[0]));
  #pragma unroll
  for(int i=0;i<4;++i){
    const int row = row0 + wv*16 + kg*4 + i;
    if(row >= n) continue;
    #pragma unroll
    for(int nn=0;nn<8;++nn){
      const int col = nn*16 + r16;
      float o = acc[nn][i];
      if(MODE & MM_BIAS) o += bvals[nn];
      if(MODE & MM_SKIP)
        o = sk*o + (1.f-sk)*base[(size_t)row*128 + col];
      if(MODE & MM_FILM){
        o += base[(size_t)row*128 + col];
        o = fgb[col]*o + fgb[128+col];
      }
      C[(size_t)row*128 + col] = o;
    }
  }
}

// multi-job mgemm: stages A ONCE, loops jobs. sel: 1 = bf16 out, 2 = KV k fp8, 3 = KV v fp8
struct MJob {
  const u16* WT;
  const float* bias;   // nullptr = none
  const float* as_;    // nullptr = no ATT epilogue
  const float* ad_;
  void* Cv;
  int att_t;
  int sel;
};
struct MJobs { MJob j[4]; };

__global__ __launch_bounds__(256) void mgemmM(const float* __restrict__ Av, MJobs jobs, int njobs,
    float* __restrict__ als8, float* __restrict__ ald8, int n){
  __shared__ u16 Al[64*128];
  __shared__ u16 Wl[128*128];
  const int tid = threadIdx.x;
  const int row0 = blockIdx.x*64;
  { // stage A once (f32 -> bf16)
    const float4* Ag = (const float4*)(Av + (size_t)row0*128);
    const int maxv = (min(64, n-row0))*32;
    #pragma unroll
    for(int j=0;j<8;++j){
      int v = tid + j*256;
      float4 val = make_float4(0.f,0.f,0.f,0.f);
      if(v < maxv) val = Ag[v];
      int row = v>>5, cb = (v&31)*8;
      uint2 st; st.x = pack2bf(val.x, val.y); st.y = pack2bf(val.z, val.w);
      *(uint2*)((char*)Al + row*256 + SWZ(row, cb)) = st;
    }
  }
  const int lane = tid & 63;
  const int wv   = tid >> 6;
  const int r16  = lane & 15;
  const int kg   = lane >> 4;
  for(int jj=0; jj<njobs; ++jj){
    const MJob job = jobs.j[jj];
    {
      const u32* Wg = (const u32*)job.WT;
      #pragma unroll
      for(int j=0;j<32;++j){
        int v = tid + j*256;
        u32 w = Wg[v];
        int row = v>>6, cb = (v&63)*4;
        *(u32*)((char*)Wl + row*256 + SWZ(row, cb)) = w;
      }
    }
    __syncthreads();
    f32x4 acc[8];
    #pragma unroll
    for(int nn=0;nn<8;++nn) acc[nn] = (f32x4){0.f,0.f,0.f,0.f};
    #pragma unroll
    for(int s=0;s<4;++s){
      const int arow = wv*16 + r16;
      const int kb = s*64 + kg*16;
      short8 af = *(const short8*)((const char*)Al + arow*256 + SWZ(arow, kb));
      #pragma unroll
      for(int nn=0;nn<8;++nn){
        const int brow = nn*16 + r16;
        short8 bf = *(const short8*)((const char*)Wl + brow*256 + SWZ(brow, kb));
        acc[nn] = __builtin_amdgcn_mfma_f32_16x16x32_bf16(af, bf, acc[nn], 0, 0, 0);
      }
    }
    if(job.as_){
      float asv[8], adv[8];
      #pragma unroll
      for(int nn=0;nn<8;++nn){ asv[nn]=job.as_[nn*16+r16]; adv[nn]=job.ad_[nn*16+r16]; }
      #pragma unroll
      for(int i=0;i<4;++i){
        const int row = row0 + wv*16 + kg*4 + i;
        #pragma unroll
        for(int h=0;h<4;++h){
          float ps = asv[2*h]*acc[2*h][i] + asv[2*h+1]*acc[2*h+1][i];
          float pd = adv[2*h]*acc[2*h][i] + adv[2*h+1]*acc[2*h+1][i];
          ps += __shfl_xor(ps,1); ps += __shfl_xor(ps,2); ps += __shfl_xor(ps,4); ps += __shfl_xor(ps,8);
          pd += __shfl_xor(pd,1); pd += __shfl_xor(pd,2); pd += __shfl_xor(pd,4); pd += __shfl_xor(pd,8);
          if(row < n && r16 == 0){
            als8[(size_t)row*8 + 2*h + job.att_t] = ps;
            ald8[(size_t)row*8 + 2*h + job.att_t] = pd;
          }
        }
      }
    }
    float bvals[8];
    #pragma unroll
    for(int nn=0;nn<8;++nn) bvals[nn] = job.bias ? job.bias[nn*16+r16] : 0.f;
    #pragma unroll
    for(int i=0;i<4;++i){
      const int row = row0 + wv*16 + kg*4 + i;
      if(row >= n) continue;
      #pragma unroll
      for(int nn=0;nn<8;++nn){
        const int col = nn*16 + r16;
        float o = acc[nn][i] + bvals[nn];
        if(job.sel == 1){
          ((u16*)job.Cv)[(size_t)row*128 + col] = f2bf(o);
        } else {
          u32 enc = __builtin_amdgcn_cvt_pk_fp8_f32(o, 0.f, 0u, false);
          ((u8*)job.Cv)[(size_t)row*256 + (col>>1)*4 + (col&1) + (job.sel-2)*2] = (u8)(enc & 0xffu);
        }
      }
    }
    __syncthreads();
  }
}

// ---------------- GAT merged gather: both types, per-type xp tables (bf16) ----------------
__global__ __launch_bounds__(256) void gat_gather3(const u16* __restrict__ xp0, const u16* __restrict__ xp1,
    const float* __restrict__ als8, const float* __restrict__ ald8,
    const int* __restrict__ jrs, const u16* __restrict__ es,
    const float* __restrict__ gb0, const float* __restrict__ gb1, float* __restrict__ out){
  const int gid = blockIdx.x*blockDim.x + threadIdx.x;
  const int node = gid >> 6;
  const int lane = threadIdx.x & 63;
  if(node >= NN) return;
  const int h = lane >> 4;
  const int cc = 2*lane;
  float o0 = gb0[cc] + gb1[cc], o1 = gb0[cc+1] + gb1[cc+1];
  #pragma unroll
  for(int t=0;t<2;++t){
    const u16* __restrict__ xp = t ? xp1 : xp0;
    const float aldv = ald8[(size_t)node*8 + 2*h + t];
    const int s0 = jrs[t*NN+node], s1 = jrs[t*NN+node+1];
    float ssum=0.f, a0=0.f, a1=0.f;
    int p = s0;
    for(; p+3<s1; p+=4){
      const int sA = es[p], sB = es[p+1], sC = es[p+2], sD = es[p+3];
      const u32 xA = *(const u32*)&xp[(size_t)sA*DD + cc];
      const u32 xB = *(const u32*)&xp[(size_t)sB*DD + cc];
      const u32 xC = *(const u32*)&xp[(size_t)sC*DD + cc];
      const u32 xD = *(const u32*)&xp[(size_t)sD*DD + cc];
      float lA = als8[(size_t)sA*8 + 2*h + t] + aldv;
      float lB = als8[(size_t)sB*8 + 2*h + t] + aldv;
      float lC = als8[(size_t)sC*8 + 2*h + t] + aldv;
      float lD = als8[(size_t)sD*8 + 2*h + t] + aldv;
      const float eA = exp2f(lA>0.f ? lA*LOG2E : lA*(0.2f*LOG2E));
      const float eB = exp2f(lB>0.f ? lB*LOG2E : lB*(0.2f*LOG2E));
      const float eC = exp2f(lC>0.f ? lC*LOG2E : lC*(0.2f*LOG2E));
      const float eD = exp2f(lD>0.f ? lD*LOG2E : lD*(0.2f*LOG2E));
      ssum += (eA+eB)+(eC+eD);
      a0 = fmaf(eA, bflo(xA), a0); a1 = fmaf(eA, bfhi(xA), a1);
      a0 = fmaf(eB, bflo(xB), a0); a1 = fmaf(eB, bfhi(xB), a1);
      a0 = fmaf(eC, bflo(xC), a0); a1 = fmaf(eC, bfhi(xC), a1);
      a0 = fmaf(eD, bflo(xD), a0); a1 = fmaf(eD, bfhi(xD), a1);
    }
    for(; p<s1; ++p){
      const int sA = es[p];
      const u32 xA = *(const u32*)&xp[(size_t)sA*DD + cc];
      float lA = als8[(size_t)sA*8 + 2*h + t] + aldv;
      const float eA = exp2f(lA>0.f ? lA*LOG2E : lA*(0.2f*LOG2E));
      ssum += eA;
      a0 = fmaf(eA, bflo(xA), a0); a1 = fmaf(eA, bfhi(xA), a1);
    }
    { // self loop (appended in reference)
      float lg = als8[(size_t)node*8 + 2*h + t] + aldv;
      const float ev = exp2f(lg>0.f ? lg*LOG2E : lg*(0.2f*LOG2E));
      ssum += ev;
      const u32 xr = *(const u32*)&xp[(size_t)node*DD + cc];
      a0 = fmaf(ev, bflo(xr), a0); a1 = fmaf(ev, bfhi(xr), a1);
    }
    const float inv = 1.f/ssum;
    o0 = fmaf(a0, inv, o0); o1 = fmaf(a1, inv, o1);
  }
  *(float2*)&out[(size_t)node*DD + cc] = make_float2(o0, o1);
}

// ---------------- BN: stats + fenced last-block finalize (deterministic, parallel tail) ----------------
__global__ __launch_bounds__(256) void bn_stats_fused(const float* __restrict__ X, float* __restrict__ part,
                               const float* __restrict__ gamma, const float* __restrict__ beta,
                               float* __restrict__ stat, int* __restrict__ counter){
  const int f = threadIdx.x & 127, rg = threadIdx.x>>7;
  float s=0.f, s2=0.f;
  for(int r = blockIdx.x*2+rg; r<NN; r += NBLK*2){
    float v = X[(size_t)r*DD+f]; s+=v; s2 = fmaf(v,v,s2);
  }
  __shared__ float ls[256], ls2[256];
  __shared__ int lastsh;
  ls[threadIdx.x]=s; ls2[threadIdx.x]=s2; __syncthreads();
  if(rg==0){
    part[blockIdx.x*256 + f]       = ls[f]+ls[128+f];
    part[blockIdx.x*256 + 128 + f] = ls2[f]+ls2[128+f];
  }
  __threadfence();
  if(threadIdx.x==0) lastsh = (atomicAdd(counter,1) == NBLK-1);
  __syncthreads();
  if(lastsh){
    __threadfence();
    float ss=0.f, ss2=0.f;
    #pragma unroll 8
    for(int bk=rg; bk<NBLK; bk+=2){
      ss  += part[bk*256 + f];
      ss2 += part[bk*256 + 128 + f];
    }
    __syncthreads();
    ls[threadIdx.x]=ss; ls2[threadIdx.x]=ss2;
    __syncthreads();
    if(rg==0){
      float S1 = ls[f]+ls[128+f], S2 = ls2[f]+ls2[128+f];
      float mu = S1/(float)NN;
      float var = S2/(float)NN - mu*mu;
      float rs = rsqrtf(var+1e-5f);
      stat[f]     = gamma[f]*rs;
      stat[128+f] = beta[f] - gamma[f]*rs*mu;
    }
    if(threadIdx.x==0) *counter = 0;
  }
}

// out = lrelu(xprev + A*acc + B)
__global__ void bn_apply_lrelu(const float* __restrict__ xprev, const float* __restrict__ acc,
                               const float* __restrict__ stat, float* __restrict__ out){
  int idx = blockIdx.x*blockDim.x+threadIdx.x;
  if(idx >= NN*64) return;
  int c = (2*idx) & 127;
  float2 x = ((const float2*)xprev)[idx];
  float2 a = ((const float2*)acc)[idx];
  float o0 = lrelu(x.x + fmaf(stat[c],   a.x, stat[128+c]));
  float o1 = lrelu(x.y + fmaf(stat[c+1], a.y, stat[128+c+1]));
  ((float2*)out)[idx] = make_float2(o0,o1);
}

// ---------------- HGT merged edge kernel: qt tables + fp8 interleaved KV ----------------
__global__ __launch_bounds__(256) void hgt_merged2(const u16* __restrict__ qt,
    const u32* __restrict__ kv, const int* __restrict__ jrs, const u16* __restrict__ es,
    const float* __restrict__ p_rel, u16* __restrict__ Sv){
  const int gid = blockIdx.x*blockDim.x + threadIdx.x;
  const int node = gid >> 6;
  const int lane = threadIdx.x & 63;
  if(node >= NN) return;
  const int h = lane >> 4;
  float acc[2][2] = {{0.f,0.f},{0.f,0.f}};
  float ssum = 0.f;
  #pragma unroll
  for(int t=0;t<2;++t){
    const u32 qw = *(const u32*)&qt[(size_t)t*NN*DD + (size_t)node*DD + 2*lane];
    const float q0 = bflo(qw), q1 = bfhi(qw);
    const float scale2 = p_rel[t*HH+h]*(0.17677669529663687f*LOG2E);
    const int s0 = jrs[t*NN+node], s1 = jrs[t*NN+node+1];
    int p = s0;
    for(; p+3<s1; p+=4){
      const int sA = es[p], sB = es[p+1], sC = es[p+2], sD = es[p+3];
      const u32 wA = kv[(size_t)sA*64 + lane];
      const u32 wB = kv[(size_t)sB*64 + lane];
      const u32 wC = kv[(size_t)sC*64 + lane];
      const u32 wD = kv[(size_t)sD*64 + lane];
      f32x2 kA = __builtin_amdgcn_cvt_pk_f32_fp8(wA, false);
      f32x2 kB = __builtin_amdgcn_cvt_pk_f32_fp8(wB, false);
      f32x2 kC = __builtin_amdgcn_cvt_pk_f32_fp8(wC, false);
      f32x2 kD = __builtin_amdgcn_cvt_pk_f32_fp8(wD, false);
      f32x2 vA = __builtin_amdgcn_cvt_pk_f32_fp8(wA, true);
      f32x2 vB = __builtin_amdgcn_cvt_pk_f32_fp8(wB, true);
      f32x2 vC = __builtin_amdgcn_cvt_pk_f32_fp8(wC, true);
      f32x2 vD = __builtin_amdgcn_cvt_pk_f32_fp8(wD, true);
      float pA = q0*kA.x + q1*kA.y;
      float pB = q0*kB.x + q1*kB.y;
      float pC = q0*kC.x + q1*kC.y;
      float pD = q0*kD.x + q1*kD.y;
      pA += __shfl_xor(pA,1); pB += __shfl_xor(pB,1); pC += __shfl_xor(pC,1); pD += __shfl_xor(pD,1);
      pA += __shfl_xor(pA,2); pB += __shfl_xor(pB,2); pC += __shfl_xor(pC,2); pD += __shfl_xor(pD,2);
      pA += __shfl_xor(pA,4); pB += __shfl_xor(pB,4); pC += __shfl_xor(pC,4); pD += __shfl_xor(pD,4);
      pA += __shfl_xor(pA,8); pB += __shfl_xor(pB,8); pC += __shfl_xor(pC,8); pD += __shfl_xor(pD,8);
      const float eA=exp2f(pA*scale2), eB=exp2f(pB*scale2);
      const float eC=exp2f(pC*scale2), eD=exp2f(pD*scale2);
      ssum += (eA+eB)+(eC+eD);
      acc[t][0] = fmaf(eA, vA.x, acc[t][0]); acc[t][1] = fmaf(eA, vA.y, acc[t][1]);
      acc[t][0] = fmaf(eB, vB.x, acc[t][0]); acc[t][1] = fmaf(eB, vB.y, acc[t][1]);
      acc[t][0] = fmaf(eC, vC.x, acc[t][0]); acc[t][1] = fmaf(eC, vC.y, acc[t][1]);
      acc[t][0] = fmaf(eD, vD.x, acc[t][0]); acc[t][1] = fmaf(eD, vD.y, acc[t][1]);
    }
    for(; p<s1; ++p){
      const int sA = es[p];
      const u32 wA = kv[(size_t)sA*64 + lane];
      f32x2 kA = __builtin_amdgcn_cvt_pk_f32_fp8(wA, false);
      f32x2 vA = __builtin_amdgcn_cvt_pk_f32_fp8(wA, true);
      float pA = q0*kA.x + q1*kA.y;
      pA += __shfl_xor(pA,1); pA += __shfl_xor(pA,2); pA += __shfl_xor(pA,4); pA += __shfl_xor(pA,8);
      const float eA = exp2f(pA*scale2);
      ssum += eA;
      acc[t][0] = fmaf(eA, vA.x, acc[t][0]); acc[t][1] = fmaf(eA, vA.y, acc[t][1]);
    }
  }
  const float inv = ssum>0.f ? 1.f/ssum : 0.f;
  ((u32*)&Sv[(size_t)node*256 +       2*lane])[0] = pack2bf(acc[0][0]*inv, acc[0][1]*inv);
  ((u32*)&Sv[(size_t)node*256 + 128 + 2*lane])[0] = pack2bf(acc[1][0]*inv, acc[1][1]*inv);
}

// ---------------- post-aggregation m_rel transform + gelu (bf16 out) ----------------
__global__ __launch_bounds__(256) void mtransform_kernel(const u16* __restrict__ Sv, const float* __restrict__ m_rel,
                                                         u16* __restrict__ out){
  __shared__ float Msh[2*HH*DHH*DHH];   // 32 KB
  for(int i=threadIdx.x;i<2*HH*DHH*DHH;i+=256) Msh[i]=m_rel[i];
  __syncthreads();
  int idx = blockIdx.x*blockDim.x + threadIdx.x;
  if(idx >= NN*DD) return;
  int node = idx>>7, f = idx&127, h = f>>5, e = f&31;
  const u16* s0p = &Sv[(size_t)node*256 + h*DHH];
  const u16* s1p = &Sv[(size_t)node*256 + 128 + h*DHH];
  const float* M0 = &Msh[(0*HH+h)*DHH*DHH + e];
  const float* M1 = &Msh[(1*HH+h)*DHH*DHH + e];
  float s = 0.f;
  #pragma unroll
  for(int d=0; d<DHH; d+=2){
    u32 w0 = *(const u32*)&s0p[d];
    u32 w1 = *(const u32*)&s1p[d];
    s = fmaf(bflo(w0), M0[d*DHH],     s);
    s = fmaf(bfhi(w0), M0[(d+1)*DHH], s);
    s = fmaf(bflo(w1), M1[d*DHH],     s);
    s = fmaf(bfhi(w1), M1[(d+1)*DHH], s);
  }
  out[idx] = f2bf(gelu_exact(s));
}

// ---------------- host ----------------
extern "C" void kernel_launch(void* const* d_in, const int* in_sizes, int n_in,
                              void* d_out, int out_size, void* d_ws, size_t ws_size,
                              hipStream_t stream){
  const float* x_cell = (const float*)d_in[0];
  const float* z_h    = (const float*)d_in[1];
  const float* x_emb  = (const float*)d_in[2];
  const int*   ei0    = (const int*)d_in[3];
  const int*   ei1    = (const int*)d_in[4];
  const float* gat_W  = (const float*)d_in[5];
  const float* gat_as = (const float*)d_in[6];
  const float* gat_ad = (const float*)d_in[7];
  const float* gat_b  = (const float*)d_in[8];
  const float* bn_g   = (const float*)d_in[9];
  const float* bn_b   = (const float*)d_in[10];
  const float* Wk = (const float*)d_in[11];
  const float* bk = (const float*)d_in[12];
  const float* Wq = (const float*)d_in[13];
  const float* bq = (const float*)d_in[14];
  const float* Wv = (const float*)d_in[15];
  const float* bv = (const float*)d_in[16];
  const float* a_rel = (const float*)d_in[17];
  const float* m_rel = (const float*)d_in[18];
  const float* p_rel = (const float*)d_in[19];
  const float* Wo = (const float*)d_in[20];
  const float* bo = (const float*)d_in[21];
  const float* skip = (const float*)d_in[22];
  const float* injW = (const float*)d_in[23];
  const float* injb = (const float*)d_in[24];
  const float* fW1 = (const float*)d_in[25];
  const float* fb1 = (const float*)d_in[26];
  const float* fW2 = (const float*)d_in[27];
  const float* fb2 = (const float*)d_in[28];

  constexpr size_t SLOT = (size_t)NN*DD;   // 6.4M elements
  float* ws = (float*)d_ws;
  float* A    = ws;                       // pre-BN acc / QT tables (bf16 x2) / mtransform bf16 out
  float* X2   = A + SLOT;                 // x1 then x2 (f32)
  float* als8 = X2 + SLOT;                // NN*8  [node][2*h+t]
  float* ald8 = als8 + (size_t)NN*8;      // NN*8
  float* bnpart = ald8 + (size_t)NN*8;    // 256*256
  float* bnstat = bnpart + 256*256;       // 256
  float* fgb    = bnstat + 256;           // 256
  float* bqt    = fgb + 256;              // 2*128
  u16* WT8  = (u16*)(bqt + 2*128);        // 8 * 128*128 bf16 (transposed weights)
  u16* WQT  = WT8 + (size_t)8*16384;      // 2 * 128*128 bf16 (folded q weights, transposed)
  u16* S    = WQT + (size_t)2*16384;      // NN*256 bf16 (HGT Sv) ; eb (u32*2EE) aliases S
  u16* XP0  = S + (size_t)NN*256;         // NN*128 bf16 (xp type0) ; fp8 KV aliases XP0
  u16* XP1  = XP0 + SLOT;                 // NN*128 bf16 (xp type1)
  u16* es   = XP1 + SLOT;                 // 2*EE u16
  int* bcnt = (int*)(es + (size_t)2*EE + 2);  // NBUCK (memset with bnctr)
  int* bnctr= bcnt + NBUCK;               // 4 ints
  int* jrs  = bnctr + 4;                  // N2+1
  int* bbase= jrs + N2 + 2;               // NBUCK+1
  int* bcur = bbase + NBUCK + 2;          // NBUCK
  size_t needed = (size_t)((char*)(bcur + NBUCK + 2) - (char*)d_ws);
  if(ws_size < needed) return;  // insufficient scratch: fail loud (poisoned d_out)

  u16* QT = (u16*)A;            // 2 bf16 qt tables alias the A slot during HGT edge phase
  u16* MT = (u16*)A;            // mtransform bf16 out (QT dead by then)
  u32* KV = (u32*)XP0;          // fp8 interleaved k/v table: NN rows x 64 u32 (12.8 MB)
  u32* EB = (u32*)S;            // bucket-sorted packed edges (4.8 MB, aliases S)

  const int TB = 256;
  dim3 b(TB);
  const int gBC    = (2*EE + 4095)/4096;
  const int gND    = (NN*DD + TB - 1)/TB;
  const int gND2   = (NN*64 + TB - 1)/TB;
  const int gNodes = (NN + 3)/4;
  const int gMG    = (NN + 63)/64;        // mgemm: 64-row tiles

  prep_all<<<258, b, 0, stream>>>(gat_W, Wk, Wv, Wo, injW, WT8, Wq, bq, a_rel, WQT, bqt,
                                  z_h, fW1, fb1, fW2, fb2, fgb);

  // joint CSR via bucket counting sort (block-aggregated reservations)
  hipMemsetAsync(bcnt, 0, (NBUCK+4)*sizeof(int), stream);   // bcnt + bnctr
  bucket_count<<<gBC, b, 0, stream>>>(ei0+EE, ei1+EE, bcnt);
  bucket_scan<<<1, 256, 0, stream>>>(bcnt, bbase, bcur);
  fill_bucket<<<gBC, b, 0, stream>>>(ei0, ei1, bcur, EB);
  fill_place<<<NBUCK, b, 0, stream>>>(EB, bbase, jrs, es);

  // ---- 2 hetero-GAT layers ----
  const float* xin = x_cell;
  for(int c=0;c<2;++c){
    MJobs gj{};
    for(int t=0;t<2;++t){
      gj.j[t].WT   = WT8 + (size_t)(c*2+t)*16384;
      gj.j[t].bias = nullptr;
      gj.j[t].as_  = gat_as + (size_t)(c*2+t)*HH*DHH;
      gj.j[t].ad_  = gat_ad + (size_t)(c*2+t)*HH*DHH;
      gj.j[t].Cv   = t? (void*)XP1 : (void*)XP0;
      gj.j[t].att_t = t;
      gj.j[t].sel  = 1;
    }
    mgemmM<<<gMG, b, 0, stream>>>(xin, gj, 2, als8, ald8, NN);
    gat_gather3<<<gNodes, b, 0, stream>>>(XP0, XP1, als8, ald8, jrs, es,
        gat_b + (size_t)(c*2+0)*DD, gat_b + (size_t)(c*2+1)*DD, A);
    bn_stats_fused<<<NBLK, b, 0, stream>>>(A, bnpart, bn_g + (size_t)c*DD, bn_b + (size_t)c*DD, bnstat, bnctr);
    bn_apply_lrelu<<<gND2, b, 0, stream>>>(xin, A, bnstat, X2);   // x1 / x2
    xin = X2;
  }
  float* x2 = X2;

  // ---- HGT ----
  {
    MJobs hj{};
    hj.j[0] = { WQT,                   bqt,       nullptr, nullptr, (void*)QT,          0, 1 };
    hj.j[1] = { WQT + 16384,           bqt + 128, nullptr, nullptr, (void*)(QT + SLOT), 0, 1 };
    hj.j[2] = { WT8 + (size_t)4*16384, bk,        nullptr, nullptr, (void*)KV,          0, 2 };
    hj.j[3] = { WT8 + (size_t)5*16384, bv,        nullptr, nullptr, (void*)KV,          0, 3 };
    mgemmM<<<gMG, b, 0, stream>>>(x2, hj, 4, nullptr, nullptr, NN);
  }
  hgt_merged2<<<gNodes, b, 0, stream>>>(QT, KV, jrs, es, p_rel, S);
  mtransform_kernel<<<gND, b, 0, stream>>>(S, m_rel, MT);   // gelu(M0^T Sv0 + M1^T Sv1) -> bf16
  mgemm<MM_ABF16|MM_BIAS|MM_SKIP><<<gMG, b, 0, stream>>>(MT, WT8 + (size_t)6*16384, bo,
      x2, nullptr, skip, (float*)d_out, NN);
  bn_stats_fused<<<NBLK, b, 0, stream>>>((float*)d_out, bnpart, bn_g + 2*DD, bn_b + 2*DD, bnstat, bnctr);
  bn_apply_lrelu<<<gND2, b, 0, stream>>>(x2, (float*)d_out, bnstat, (float*)d_out);  // x3c in place
  mgemm<MM_BIAS|MM_FILM><<<gMG, b, 0, stream>>>(x_emb, WT8 + (size_t)7*16384, injb,
      (float*)d_out, fgb, nullptr, (float*)d_out, NN);
}